// Round 1
// baseline (283.502 us; speedup 1.0000x reference)
//
#include <hip/hip_runtime.h>
#include <hip/hip_bf16.h>
#include <stdint.h>

typedef _Float16 half8 __attribute__((ext_vector_type(8)));
typedef float floatx4 __attribute__((ext_vector_type(4)));

#define SCALE 0.14433756729740643f

// ws layout (bytes):
// Q  f16 [8][8][1024][64]   off 0          (8,388,608)  cols: 0..23 q1, 24..31 zero, 32..55 q2, 56..63 zero
// K  f16 [8][8][1024][64]   off 8388608    same column layout
// V  f16 [8][8][64][1024]   off 16777216   rows 0..47 v, row 48 ones, 49..63 zero
// Y  f32 [8][384][1024]     off 25165824   (12,582,912) scrambled pre-proj tensor
// partial f32 [128][2]      off 37748736

// ---------------- init: K pad cols, V pad rows ----------------
__global__ void k_init(_Float16* __restrict__ Kt, _Float16* __restrict__ V) {
  int tid = blockIdx.x * 256 + threadIdx.x;
  half8 z = {(_Float16)0,(_Float16)0,(_Float16)0,(_Float16)0,(_Float16)0,(_Float16)0,(_Float16)0,(_Float16)0};
  if (tid < 65536) {
    _Float16* row = Kt + (long)tid * 64;
    *(half8*)(row + 24) = z;
    *(half8*)(row + 56) = z;
  } else {
    int t = tid - 65536;            // 65536 tasks: 64 bh * 1024 chunks of 16
    int bh = t >> 10, k = t & 1023;
    _Float16* p = V + (long)bh * 65536 + 49152 + k * 16;
    if (k < 64) {                   // row 48 = ones
      half8 one = {(_Float16)1,(_Float16)1,(_Float16)1,(_Float16)1,(_Float16)1,(_Float16)1,(_Float16)1,(_Float16)1};
      *(half8*)p = one; *(half8*)(p + 8) = one;
    } else {
      *(half8*)p = z; *(half8*)(p + 8) = z;
    }
  }
}

// ---------------- QKV GEMM: qkv_w(1152x384) @ x(384x1024) per batch ----------------
__launch_bounds__(256)
__global__ void k_qkv(const float* __restrict__ X, const float* __restrict__ W,
                      _Float16* __restrict__ Q, _Float16* __restrict__ Kt,
                      _Float16* __restrict__ V) {
  const int tid = threadIdx.x;
  const int lane = tid & 63;
  const int wv = tid >> 6;
  const int l15 = lane & 15;
  const int g = lane >> 4;
  const int o0 = blockIdx.x * 48;   // 24 o-blocks (one head-slice each)
  const int n0 = blockIdx.y * 64;   // 16 n-blocks
  const int b = blockIdx.z;
  const float* Xb = X + (long)b * 384 * 1024;

  floatx4 zero4 = {0.f, 0.f, 0.f, 0.f};
  floatx4 acc[3];
  acc[0] = zero4; acc[1] = zero4; acc[2] = zero4;

  const int ncol = n0 + wv * 16 + l15;
  for (int c0 = 0; c0 < 384; c0 += 32) {
    half8 bfrag;
    const float* xp = Xb + (long)(c0 + g * 8) * 1024 + ncol;
    #pragma unroll
    for (int j = 0; j < 8; j++) bfrag[j] = (_Float16)xp[j * 1024];
    #pragma unroll
    for (int rt = 0; rt < 3; rt++) {
      const float* wp = W + (o0 + rt * 16 + l15) * 384 + c0 + g * 8;
      floatx4 w0 = *(const floatx4*)wp;
      floatx4 w1 = *(const floatx4*)(wp + 4);
      half8 afrag;
      #pragma unroll
      for (int j = 0; j < 4; j++) { afrag[j] = (_Float16)w0[j]; afrag[j+4] = (_Float16)w1[j]; }
      acc[rt] = __builtin_amdgcn_mfma_f32_16x16x32_f16(afrag, bfrag, acc[rt], 0, 0, 0);
    }
  }

  __shared__ __align__(16) _Float16 T[3456];   // max(64*52, 48*72)

  if (o0 < 768) {
    // q or k rows: dump transposed T[n(64)][o(48), stride 52]
    #pragma unroll
    for (int rt = 0; rt < 3; rt++)
      #pragma unroll
      for (int r = 0; r < 4; r++)
        T[(wv * 16 + l15) * 52 + rt * 16 + g * 4 + r] = (_Float16)acc[rt][r];
    __syncthreads();
    if (tid < 128) {
      int n_ = tid >> 1, part = tid & 1;   // part0: d48 0..23 -> cols 0..23 ; part1: 24..47 -> cols 32..55
      int qk = o0 >= 384;
      int hh = (o0 - qk * 384) / 48;
      _Float16* dst = (qk ? Kt : Q) + ((long)((b * 8 + hh) * 1024 + n0 + n_)) * 64 + part * 32;
      const _Float16* src = T + n_ * 52 + part * 24;
      uint32_t buf[12];
      #pragma unroll
      for (int i = 0; i < 12; i++) {
        union { _Float16 h[2]; uint32_t u; } cv;
        cv.h[0] = src[2*i]; cv.h[1] = src[2*i+1];
        buf[i] = cv.u;
      }
      #pragma unroll
      for (int i = 0; i < 3; i++) {
        uint4 v; v.x = buf[4*i]; v.y = buf[4*i+1]; v.z = buf[4*i+2]; v.w = buf[4*i+3];
        ((uint4*)dst)[i] = v;
      }
    }
  } else {
    // v rows: natural dump T[o(48)][n(64), stride 72]
    #pragma unroll
    for (int rt = 0; rt < 3; rt++)
      #pragma unroll
      for (int r = 0; r < 4; r++)
        T[(rt * 16 + g * 4 + r) * 72 + wv * 16 + l15] = (_Float16)acc[rt][r];
    __syncthreads();
    if (tid < 192) {
      int row = tid >> 2, seg = tid & 3;
      int oo = o0 - 768 + row;
      int hh = oo / 48, d48 = oo % 48;
      _Float16* dst = V + ((long)((b * 8 + hh) * 64 + d48)) * 1024 + n0 + seg * 16;
      half8 v0 = *(const half8*)(T + row * 72 + seg * 16);
      half8 v1 = *(const half8*)(T + row * 72 + seg * 16 + 8);
      *(half8*)dst = v0;
      *(half8*)(dst + 8) = v1;
    }
  }
}

// ---------------- GroupNorm stats (deterministic chunked partials) ----------------
__global__ void k_gnstats(const _Float16* __restrict__ Q, float* __restrict__ partial) {
  int bg = blockIdx.x >> 3;        // (b*2+grp)
  int chunk = blockIdx.x & 7;
  int b = bg >> 1, grp = bg & 1;
  float s1 = 0.f, s2 = 0.f;
  for (int rr = chunk * 512 + threadIdx.x; rr < chunk * 512 + 512; rr += 256) {
    int h = grp * 4 + (rr >> 10);
    int n = rr & 1023;
    const _Float16* p = Q + ((long)((b * 8 + h) * 1024 + n)) * 64 + 32;
    #pragma unroll
    for (int s = 0; s < 3; s++) {
      half8 v = *(const half8*)(p + s * 8);
      #pragma unroll
      for (int j = 0; j < 8; j++) { float f = (float)v[j]; s1 += f; s2 += f * f; }
    }
  }
  #pragma unroll
  for (int off = 32; off > 0; off >>= 1) {
    s1 += __shfl_down(s1, off);
    s2 += __shfl_down(s2, off);
  }
  __shared__ float red[8];
  int wv = threadIdx.x >> 6;
  if ((threadIdx.x & 63) == 0) { red[wv] = s1; red[4 + wv] = s2; }
  __syncthreads();
  if (threadIdx.x == 0) {
    float S1 = red[0] + red[1] + red[2] + red[3];
    float S2 = red[4] + red[5] + red[6] + red[7];
    partial[blockIdx.x * 2]     = S1;
    partial[blockIdx.x * 2 + 1] = S2;
  }
}

// ---------------- GN apply + fold scales into Q, write zero pads ----------------
__global__ void k_gnapply(_Float16* __restrict__ Q, const float* __restrict__ partial,
                          const float* __restrict__ lam, const float* __restrict__ gw,
                          const float* __restrict__ gb) {
  int r = blockIdx.x * 256 + threadIdx.x;   // (b,h,n) row id, 65536 total
  int h = (r >> 10) & 7;
  int grp = h >> 2;
  int b = r >> 13;
  const float* pp = partial + (b * 2 + grp) * 16;
  float S1 = 0.f, S2 = 0.f;
  #pragma unroll
  for (int i = 0; i < 8; i++) { S1 += pp[2*i]; S2 += pp[2*i+1]; }
  float mean = S1 * (1.f / 98304.f);
  float rstd = rsqrtf(S2 * (1.f / 98304.f) - mean * mean + 1e-5f);
  float sl = SCALE * lam[h];
  _Float16* row = Q + (long)r * 64;
  half8 z = {(_Float16)0,(_Float16)0,(_Float16)0,(_Float16)0,(_Float16)0,(_Float16)0,(_Float16)0,(_Float16)0};
  #pragma unroll
  for (int s = 0; s < 3; s++) {          // q1 *= scale
    half8 v = *(half8*)(row + s * 8);
    #pragma unroll
    for (int j = 0; j < 8; j++) v[j] = (_Float16)((float)v[j] * SCALE);
    *(half8*)(row + s * 8) = v;
  }
  *(half8*)(row + 24) = z;
  #pragma unroll
  for (int s = 0; s < 3; s++) {          // q2 -> ((q2-m)*rstd*g + b) * scale*lambda
    half8 v = *(half8*)(row + 32 + s * 8);
    #pragma unroll
    for (int j = 0; j < 8; j++) {
      int c = s * 8 + j;
      v[j] = (_Float16)((((float)v[j] - mean) * rstd * gw[h * 24 + c] + gb[h * 24 + c]) * sl);
    }
    *(half8*)(row + 32 + s * 8) = v;
  }
  *(half8*)(row + 56) = z;
}

// ---------------- fused dual-softmax attention ----------------
__launch_bounds__(256)
__global__ void k_attn(const _Float16* __restrict__ Q, const _Float16* __restrict__ K,
                       const _Float16* __restrict__ V, float* __restrict__ Y) {
  const int tid = threadIdx.x;
  const int lane = tid & 63;
  const int wv = tid >> 6;
  const int l15 = lane & 15;
  const int g = lane >> 4;
  const int b = blockIdx.z, h = blockIdx.y;
  const int n0 = blockIdx.x * 64;

  const _Float16* Qbh = Q + (long)(b * 8 + h) * 65536;
  const _Float16* Kbh = K + (long)(b * 8 + h) * 65536;
  const _Float16* Vbh = V + (long)(b * 8 + h) * 65536;

  __shared__ __align__(16) char smem[26624];
  _Float16 (*P1)[72] = (_Float16(*)[72])smem;            // 64x72 f16 = 9216
  _Float16 (*P2)[72] = (_Float16(*)[72])(smem + 9216);
  float (*A1l)[52] = (float(*)[52])smem;                 // reuse after loop: 64x52 f32
  float (*A2l)[52] = (float(*)[52])(smem + 13312);

  const int qrow = n0 + wv * 16 + l15;
  half8 a1 = *(const half8*)(Qbh + qrow * 64 + g * 8);       // q1 (cols 0..31, padded)
  half8 a2 = *(const half8*)(Qbh + qrow * 64 + 32 + g * 8);  // q2n (cols 32..63)

  floatx4 zero4 = {0.f, 0.f, 0.f, 0.f};
  floatx4 acc1[4], acc2[4];
  #pragma unroll
  for (int i = 0; i < 4; i++) { acc1[i] = zero4; acc2[i] = zero4; }

  for (int m0 = 0; m0 < 1024; m0 += 64) {
    // QK^T for this wave's 16 rows x 64 cols, both parts; exp to LDS (f16)
    #pragma unroll
    for (int mt = 0; mt < 4; mt++) {
      const _Float16* kp = Kbh + (long)(m0 + mt * 16 + l15) * 64;
      half8 bk1 = *(const half8*)(kp + g * 8);
      half8 bk2 = *(const half8*)(kp + 32 + g * 8);
      floatx4 s1 = __builtin_amdgcn_mfma_f32_16x16x32_f16(a1, bk1, zero4, 0, 0, 0);
      floatx4 s2 = __builtin_amdgcn_mfma_f32_16x16x32_f16(a2, bk2, zero4, 0, 0, 0);
      #pragma unroll
      for (int r = 0; r < 4; r++) {
        P1[wv * 16 + g * 4 + r][mt * 16 + l15] = (_Float16)__expf(s1[r]);
        P2[wv * 16 + g * 4 + r][mt * 16 + l15] = (_Float16)__expf(s2[r]);
      }
    }
    __syncthreads();
    // PV: acc[part][ct] over V rows (0..47 = v, 48 = ones -> denominators)
    #pragma unroll
    for (int kc = 0; kc < 2; kc++) {
      half8 pa1 = *(const half8*)(&P1[wv * 16 + l15][kc * 32 + g * 8]);
      half8 pa2 = *(const half8*)(&P2[wv * 16 + l15][kc * 32 + g * 8]);
      #pragma unroll
      for (int ct = 0; ct < 4; ct++) {
        half8 bv = *(const half8*)(Vbh + (long)(ct * 16 + l15) * 1024 + m0 + kc * 32 + g * 8);
        acc1[ct] = __builtin_amdgcn_mfma_f32_16x16x32_f16(pa1, bv, acc1[ct], 0, 0, 0);
        acc2[ct] = __builtin_amdgcn_mfma_f32_16x16x32_f16(pa2, bv, acc2[ct], 0, 0, 0);
      }
    }
    __syncthreads();
  }

  // dump accumulators, form diff, write Y in the scrambled layout (which is linear per (b,h))
  #pragma unroll
  for (int ct = 0; ct < 4; ct++) {
    int col = ct * 16 + l15;
    if (col < 49) {
      #pragma unroll
      for (int r = 0; r < 4; r++) {
        A1l[wv * 16 + g * 4 + r][col] = acc1[ct][r];
        A2l[wv * 16 + g * 4 + r][col] = acc2[ct][r];
      }
    }
  }
  __syncthreads();
  {
    int row = tid >> 2, q = tid & 3;    // each thread: 12 of 48 output dims for one row
    float inv1 = 1.f / A1l[row][48];
    float inv2 = 1.f / A2l[row][48];
    float vals[12];
    #pragma unroll
    for (int j = 0; j < 12; j++) {
      int d = q * 12 + j;
      vals[j] = A1l[row][d] * inv1 - A2l[row][d] * inv2;
    }
    int p = q >> 1;   // d<24 -> out1 block, else out2 block
    long off = (long)(b * 8 + h) * 49152 + (long)p * 24576 + (long)(n0 + row) * 24 + (q & 1) * 12;
    float* dst = Y + off;
    #pragma unroll
    for (int i = 0; i < 3; i++) {
      floatx4 v; v[0] = vals[4*i]; v[1] = vals[4*i+1]; v[2] = vals[4*i+2]; v[3] = vals[4*i+3];
      *(floatx4*)(dst + 4 * i) = v;
    }
  }
}

// ---------------- proj GEMM: proj_w(384x384) @ Y(384x1024) + b ----------------
__launch_bounds__(256)
__global__ void k_proj(const float* __restrict__ Y, const float* __restrict__ PW,
                       const float* __restrict__ PB, float* __restrict__ out) {
  const int tid = threadIdx.x, lane = tid & 63, wv = tid >> 6, l15 = lane & 15, g = lane >> 4;
  const int o0 = blockIdx.x * 64, m0 = blockIdx.y * 64, b = blockIdx.z;
  const float* Yb = Y + (long)b * 393216;
  floatx4 zero4 = {0.f, 0.f, 0.f, 0.f};
  floatx4 acc[4];
  #pragma unroll
  for (int i = 0; i < 4; i++) acc[i] = zero4;
  const int mcol = m0 + wv * 16 + l15;
  for (int c0 = 0; c0 < 384; c0 += 32) {
    half8 bfrag;
    const float* yp = Yb + (long)(c0 + g * 8) * 1024 + mcol;
    #pragma unroll
    for (int j = 0; j < 8; j++) bfrag[j] = (_Float16)yp[j * 1024];
    #pragma unroll
    for (int rt = 0; rt < 4; rt++) {
      const float* wp = PW + (o0 + rt * 16 + l15) * 384 + c0 + g * 8;
      floatx4 w0 = *(const floatx4*)wp;
      floatx4 w1 = *(const floatx4*)(wp + 4);
      half8 afrag;
      #pragma unroll
      for (int j = 0; j < 4; j++) { afrag[j] = (_Float16)w0[j]; afrag[j+4] = (_Float16)w1[j]; }
      acc[rt] = __builtin_amdgcn_mfma_f32_16x16x32_f16(afrag, bfrag, acc[rt], 0, 0, 0);
    }
  }
  #pragma unroll
  for (int rt = 0; rt < 4; rt++) {
    int o_ = o0 + rt * 16 + g * 4;
    #pragma unroll
    for (int r = 0; r < 4; r++) {
      out[(long)(b * 384 + o_ + r) * 1024 + mcol] = acc[rt][r] + PB[o_ + r];
    }
  }
}

extern "C" void kernel_launch(void* const* d_in, const int* in_sizes, int n_in,
                              void* d_out, int out_size, void* d_ws, size_t ws_size,
                              hipStream_t stream) {
  const float* x     = (const float*)d_in[0];
  const float* qkv_w = (const float*)d_in[1];
  const float* lam   = (const float*)d_in[2];
  const float* gw    = (const float*)d_in[3];
  const float* gb    = (const float*)d_in[4];
  const float* pw    = (const float*)d_in[5];
  const float* pb    = (const float*)d_in[6];
  float* out = (float*)d_out;
  char* ws = (char*)d_ws;
  _Float16* Q  = (_Float16*)ws;
  _Float16* Kt = (_Float16*)(ws + 8388608);
  _Float16* V  = (_Float16*)(ws + 16777216);
  float* Y       = (float*)(ws + 25165824);
  float* partial = (float*)(ws + 37748736);

  hipLaunchKernelGGL(k_init,    dim3(512),       dim3(256), 0, stream, Kt, V);
  hipLaunchKernelGGL(k_qkv,     dim3(24, 16, 8), dim3(256), 0, stream, x, qkv_w, Q, Kt, V);
  hipLaunchKernelGGL(k_gnstats, dim3(128),       dim3(256), 0, stream, Q, partial);
  hipLaunchKernelGGL(k_gnapply, dim3(256),       dim3(256), 0, stream, Q, partial, lam, gw, gb);
  hipLaunchKernelGGL(k_attn,    dim3(16, 8, 8),  dim3(256), 0, stream, Q, Kt, V, Y);
  hipLaunchKernelGGL(k_proj,    dim3(6, 16, 8),  dim3(256), 0, stream, Y, pw, pb, out);
}

// Round 4
// 256.097 us; speedup vs baseline: 1.1070x; 1.1070x over previous
//
#include <hip/hip_runtime.h>
#include <hip/hip_bf16.h>
#include <stdint.h>

typedef _Float16 half8 __attribute__((ext_vector_type(8)));
typedef _Float16 half4 __attribute__((ext_vector_type(4)));
typedef __fp16 fp16x2 __attribute__((ext_vector_type(2)));
typedef float floatx4 __attribute__((ext_vector_type(4)));
typedef float floatx16 __attribute__((ext_vector_type(16)));

#define SCALE 0.14433756729740643f
#define LOG2E 1.4426950408889634f

// ws layout (bytes):
// Q  f16 [8][8][1024][64]   off 0          cols: 0..23 q1, 24..31 zero, 32..55 q2, 56..63 zero
// K  f16 [8][8][1024][64]   off 8388608    same column layout
// V  f16 [8][8][64][1024]   off 16777216   rows 0..47 v, row 48 ones, 49..63 zero
// Y  f32 [8][384][1024]     off 25165824   scrambled pre-proj tensor
// partial f32 [128][2]      off 37748736

__device__ inline float fexp2(float x) {
  return __builtin_exp2f(x);
}

__device__ inline uint32_t pkrtz(float a, float b) {
  fp16x2 h = __builtin_amdgcn_cvt_pkrtz(a, b);
  union { fp16x2 h; uint32_t u; } cv; cv.h = h; return cv.u;
}

// V B-fragment load matching the natural (no-permlane) P element order:
// element j <-> m-offset hi*4 + (j&3) + 8*(j>>2); p already points at +hi*4.
__device__ inline half8 ldv(const _Float16* p) {
  half4 a = *(const half4*)p;
  half4 b = *(const half4*)(p + 8);
  half8 r;
  r[0] = a[0]; r[1] = a[1]; r[2] = a[2]; r[3] = a[3];
  r[4] = b[0]; r[5] = b[1]; r[6] = b[2]; r[7] = b[3];
  return r;
}

// ---------------- init: K pad cols, V pad rows ----------------
__global__ void k_init(_Float16* __restrict__ Kt, _Float16* __restrict__ V) {
  int tid = blockIdx.x * 256 + threadIdx.x;
  half8 z = {(_Float16)0,(_Float16)0,(_Float16)0,(_Float16)0,(_Float16)0,(_Float16)0,(_Float16)0,(_Float16)0};
  if (tid < 65536) {
    _Float16* row = Kt + (long)tid * 64;
    *(half8*)(row + 24) = z;
    *(half8*)(row + 56) = z;
  } else {
    int t = tid - 65536;            // 65536 tasks: 64 bh * 1024 chunks of 16
    int bh = t >> 10, k = t & 1023;
    _Float16* p = V + (long)bh * 65536 + 49152 + k * 16;
    if (k < 64) {                   // row 48 = ones
      half8 one = {(_Float16)1,(_Float16)1,(_Float16)1,(_Float16)1,(_Float16)1,(_Float16)1,(_Float16)1,(_Float16)1};
      *(half8*)p = one; *(half8*)(p + 8) = one;
    } else {
      *(half8*)p = z; *(half8*)(p + 8) = z;
    }
  }
}

// ---------------- QKV GEMM: qkv_w(1152x384) @ x(384x1024) per batch ----------------
__launch_bounds__(256)
__global__ void k_qkv(const float* __restrict__ X, const float* __restrict__ W,
                      _Float16* __restrict__ Q, _Float16* __restrict__ Kt,
                      _Float16* __restrict__ V) {
  const int tid = threadIdx.x;
  const int lane = tid & 63;
  const int wv = tid >> 6;
  const int l15 = lane & 15;
  const int g = lane >> 4;
  const int o0 = blockIdx.x * 48;   // 24 o-blocks (one head-slice each)
  const int n0 = blockIdx.y * 64;   // 16 n-blocks
  const int b = blockIdx.z;
  const float* Xb = X + (long)b * 384 * 1024;

  floatx4 zero4 = {0.f, 0.f, 0.f, 0.f};
  floatx4 acc[3];
  acc[0] = zero4; acc[1] = zero4; acc[2] = zero4;

  const int ncol = n0 + wv * 16 + l15;
  for (int c0 = 0; c0 < 384; c0 += 32) {
    half8 bfrag;
    const float* xp = Xb + (long)(c0 + g * 8) * 1024 + ncol;
    #pragma unroll
    for (int j = 0; j < 8; j++) bfrag[j] = (_Float16)xp[j * 1024];
    #pragma unroll
    for (int rt = 0; rt < 3; rt++) {
      const float* wp = W + (o0 + rt * 16 + l15) * 384 + c0 + g * 8;
      floatx4 w0 = *(const floatx4*)wp;
      floatx4 w1 = *(const floatx4*)(wp + 4);
      half8 afrag;
      #pragma unroll
      for (int j = 0; j < 4; j++) { afrag[j] = (_Float16)w0[j]; afrag[j+4] = (_Float16)w1[j]; }
      acc[rt] = __builtin_amdgcn_mfma_f32_16x16x32_f16(afrag, bfrag, acc[rt], 0, 0, 0);
    }
  }

  __shared__ __align__(16) _Float16 T[3456];   // max(64*52, 48*72)

  if (o0 < 768) {
    // q or k rows: dump transposed T[n(64)][o(48), stride 52]
    #pragma unroll
    for (int rt = 0; rt < 3; rt++)
      #pragma unroll
      for (int r = 0; r < 4; r++)
        T[(wv * 16 + l15) * 52 + rt * 16 + g * 4 + r] = (_Float16)acc[rt][r];
    __syncthreads();
    if (tid < 128) {
      int n_ = tid >> 1, part = tid & 1;   // part0: d48 0..23 -> cols 0..23 ; part1: 24..47 -> cols 32..55
      int qk = o0 >= 384;
      int hh = (o0 - qk * 384) / 48;
      _Float16* dst = (qk ? Kt : Q) + ((long)((b * 8 + hh) * 1024 + n0 + n_)) * 64 + part * 32;
      const _Float16* src = T + n_ * 52 + part * 24;
      uint32_t buf[12];
      #pragma unroll
      for (int i = 0; i < 12; i++) {
        union { _Float16 h[2]; uint32_t u; } cv;
        cv.h[0] = src[2*i]; cv.h[1] = src[2*i+1];
        buf[i] = cv.u;
      }
      #pragma unroll
      for (int i = 0; i < 3; i++) {
        uint4 v; v.x = buf[4*i]; v.y = buf[4*i+1]; v.z = buf[4*i+2]; v.w = buf[4*i+3];
        ((uint4*)dst)[i] = v;
      }
    }
  } else {
    // v rows: natural dump T[o(48)][n(64), stride 72]
    #pragma unroll
    for (int rt = 0; rt < 3; rt++)
      #pragma unroll
      for (int r = 0; r < 4; r++)
        T[(rt * 16 + g * 4 + r) * 72 + wv * 16 + l15] = (_Float16)acc[rt][r];
    __syncthreads();
    if (tid < 192) {
      int row = tid >> 2, seg = tid & 3;
      int oo = o0 - 768 + row;
      int hh = oo / 48, d48 = oo % 48;
      _Float16* dst = V + ((long)((b * 8 + hh) * 64 + d48)) * 1024 + n0 + seg * 16;
      half8 v0 = *(const half8*)(T + row * 72 + seg * 16);
      half8 v1 = *(const half8*)(T + row * 72 + seg * 16 + 8);
      *(half8*)dst = v0;
      *(half8*)(dst + 8) = v1;
    }
  }
}

// ---------------- GroupNorm stats (deterministic chunked partials) ----------------
__global__ void k_gnstats(const _Float16* __restrict__ Q, float* __restrict__ partial) {
  int bg = blockIdx.x >> 3;        // (b*2+grp)
  int chunk = blockIdx.x & 7;
  int b = bg >> 1, grp = bg & 1;
  float s1 = 0.f, s2 = 0.f;
  for (int rr = chunk * 512 + threadIdx.x; rr < chunk * 512 + 512; rr += 256) {
    int h = grp * 4 + (rr >> 10);
    int n = rr & 1023;
    const _Float16* p = Q + ((long)((b * 8 + h) * 1024 + n)) * 64 + 32;
    #pragma unroll
    for (int s = 0; s < 3; s++) {
      half8 v = *(const half8*)(p + s * 8);
      #pragma unroll
      for (int j = 0; j < 8; j++) { float f = (float)v[j]; s1 += f; s2 += f * f; }
    }
  }
  #pragma unroll
  for (int off = 32; off > 0; off >>= 1) {
    s1 += __shfl_down(s1, off);
    s2 += __shfl_down(s2, off);
  }
  __shared__ float red[8];
  int wv = threadIdx.x >> 6;
  if ((threadIdx.x & 63) == 0) { red[wv] = s1; red[4 + wv] = s2; }
  __syncthreads();
  if (threadIdx.x == 0) {
    float S1 = red[0] + red[1] + red[2] + red[3];
    float S2 = red[4] + red[5] + red[6] + red[7];
    partial[blockIdx.x * 2]     = S1;
    partial[blockIdx.x * 2 + 1] = S2;
  }
}

// ---------------- GN apply + fold scale*log2e into Q, write zero pads ----------------
__global__ void k_gnapply(_Float16* __restrict__ Q, const float* __restrict__ partial,
                          const float* __restrict__ lam, const float* __restrict__ gw,
                          const float* __restrict__ gb) {
  int r = blockIdx.x * 256 + threadIdx.x;   // (b,h,n) row id, 65536 total
  int h = (r >> 10) & 7;
  int grp = h >> 2;
  int b = r >> 13;
  const float* pp = partial + (b * 2 + grp) * 16;
  float S1 = 0.f, S2 = 0.f;
  #pragma unroll
  for (int i = 0; i < 8; i++) { S1 += pp[2*i]; S2 += pp[2*i+1]; }
  float mean = S1 * (1.f / 98304.f);
  float rstd = rsqrtf(S2 * (1.f / 98304.f) - mean * mean + 1e-5f);
  const float s1s = SCALE * LOG2E;
  float sl = s1s * lam[h];
  _Float16* row = Q + (long)r * 64;
  half8 z = {(_Float16)0,(_Float16)0,(_Float16)0,(_Float16)0,(_Float16)0,(_Float16)0,(_Float16)0,(_Float16)0};
  #pragma unroll
  for (int s = 0; s < 3; s++) {          // q1 *= scale*log2e
    half8 v = *(half8*)(row + s * 8);
    #pragma unroll
    for (int j = 0; j < 8; j++) v[j] = (_Float16)((float)v[j] * s1s);
    *(half8*)(row + s * 8) = v;
  }
  *(half8*)(row + 24) = z;
  #pragma unroll
  for (int s = 0; s < 3; s++) {          // q2 -> ((q2-m)*rstd*g + b) * scale*lambda*log2e
    half8 v = *(half8*)(row + 32 + s * 8);
    #pragma unroll
    for (int j = 0; j < 8; j++) {
      int c = s * 8 + j;
      v[j] = (_Float16)((((float)v[j] - mean) * rstd * gw[h * 24 + c] + gb[h * 24 + c]) * sl);
    }
    *(half8*)(row + 32 + s * 8) = v;
  }
  *(half8*)(row + 56) = z;
}

// ---------------- fused dual-softmax attention: barrier-free, 1 wave / 32 q-rows ----
// Swapped QK^T with 32x32x16 f16 MFMA: S^T[m][n], lane holds n = lane&31,
// m = (r&3)+8*(r>>2)+4*(lane>>5) per 32-m window. exp2 -> pkrtz pairs used in
// natural register order as the PV A-fragment; the cross-lane m permutation is
// absorbed into V's per-lane addressing (two half4 loads at +hi*4 and +8+hi*4),
// so correctness is independent of the HW k-mapping and needs no permlane.
// V ones-row at d=48 produces softmax denominators inside the PV accumulators.
__launch_bounds__(64, 2)
__global__ void k_attn(const _Float16* __restrict__ Q, const _Float16* __restrict__ K,
                       const _Float16* __restrict__ V, float* __restrict__ Y) {
  const int lane = threadIdx.x;
  const int l31 = lane & 31;
  const int hi = lane >> 5;
  const int b = blockIdx.z, h = blockIdx.y;
  const int n0 = blockIdx.x * 32;

  const _Float16* Qbh = Q + (long)(b * 8 + h) * 65536;
  const _Float16* Kbh = K + (long)(b * 8 + h) * 65536;
  const _Float16* Vbh = V + (long)(b * 8 + h) * 65536;

  const _Float16* qp = Qbh + (n0 + l31) * 64 + hi * 8;
  half8 qf0 = *(const half8*)(qp);        // d 0..15   (q1)
  half8 qf1 = *(const half8*)(qp + 16);   // d 16..31  (q1 tail + pad)
  half8 qf2 = *(const half8*)(qp + 32);   // d 32..47  (q2n)
  half8 qf3 = *(const half8*)(qp + 48);   // d 48..63  (q2n tail + pad)

  floatx16 z16;
  #pragma unroll
  for (int i = 0; i < 16; i++) z16[i] = 0.f;
  floatx16 acc00 = z16, acc01 = z16, acc10 = z16, acc11 = z16;

  #pragma unroll 2
  for (int m0 = 0; m0 < 1024; m0 += 32) {
    const _Float16* kp = Kbh + (m0 + l31) * 64 + hi * 8;
    half8 kf0 = *(const half8*)(kp);
    half8 kf1 = *(const half8*)(kp + 16);
    half8 kf2 = *(const half8*)(kp + 32);
    half8 kf3 = *(const half8*)(kp + 48);

    floatx16 s1 = __builtin_amdgcn_mfma_f32_32x32x16_f16(kf0, qf0, z16, 0, 0, 0);
    s1 = __builtin_amdgcn_mfma_f32_32x32x16_f16(kf1, qf1, s1, 0, 0, 0);
    floatx16 s2 = __builtin_amdgcn_mfma_f32_32x32x16_f16(kf2, qf2, z16, 0, 0, 0);
    s2 = __builtin_amdgcn_mfma_f32_32x32x16_f16(kf3, qf3, s2, 0, 0, 0);

    // V B-frags in natural-P element order (issued early; consumed after exp/pack)
    const _Float16* vp = Vbh + l31 * 1024 + m0 + hi * 4;
    half8 vf00 = ldv(vp);                  // d-tile0, m-chunk0
    half8 vf01 = ldv(vp + 16);             // d-tile0, m-chunk1
    half8 vf10 = ldv(vp + 32768);          // d-tile1, m-chunk0
    half8 vf11 = ldv(vp + 32768 + 16);     // d-tile1, m-chunk1

    // exp2 + pack pairs; natural register order IS the A-frag order now
    uint32_t u1[8], u2[8];
    #pragma unroll
    for (int q = 0; q < 8; q++) {
      u1[q] = pkrtz(fexp2(s1[2 * q]), fexp2(s1[2 * q + 1]));
      u2[q] = pkrtz(fexp2(s2[2 * q]), fexp2(s2[2 * q + 1]));
    }

    union { uint32_t u[4]; half8 h; } pa;
    pa.u[0] = u1[0]; pa.u[1] = u1[1]; pa.u[2] = u1[2]; pa.u[3] = u1[3];
    half8 p1c0 = pa.h;
    pa.u[0] = u1[4]; pa.u[1] = u1[5]; pa.u[2] = u1[6]; pa.u[3] = u1[7];
    half8 p1c1 = pa.h;
    pa.u[0] = u2[0]; pa.u[1] = u2[1]; pa.u[2] = u2[2]; pa.u[3] = u2[3];
    half8 p2c0 = pa.h;
    pa.u[0] = u2[4]; pa.u[1] = u2[5]; pa.u[2] = u2[6]; pa.u[3] = u2[7];
    half8 p2c1 = pa.h;

    acc00 = __builtin_amdgcn_mfma_f32_32x32x16_f16(p1c0, vf00, acc00, 0, 0, 0);
    acc00 = __builtin_amdgcn_mfma_f32_32x32x16_f16(p1c1, vf01, acc00, 0, 0, 0);
    acc01 = __builtin_amdgcn_mfma_f32_32x32x16_f16(p1c0, vf10, acc01, 0, 0, 0);
    acc01 = __builtin_amdgcn_mfma_f32_32x32x16_f16(p1c1, vf11, acc01, 0, 0, 0);
    acc10 = __builtin_amdgcn_mfma_f32_32x32x16_f16(p2c0, vf00, acc10, 0, 0, 0);
    acc10 = __builtin_amdgcn_mfma_f32_32x32x16_f16(p2c1, vf01, acc10, 0, 0, 0);
    acc11 = __builtin_amdgcn_mfma_f32_32x32x16_f16(p2c0, vf10, acc11, 0, 0, 0);
    acc11 = __builtin_amdgcn_mfma_f32_32x32x16_f16(p2c1, vf11, acc11, 0, 0, 0);
  }

  // epilogue: denominators live in acc*1 (d-tile1) col 48 -> lanes with l31==16
  float* Ybh = Y + (long)(b * 8 + h) * 49152;
  const int src = (lane & 32) + 16;
  #pragma unroll
  for (int r = 0; r < 16; r++) {
    float i1 = __builtin_amdgcn_rcpf(__shfl(acc01[r], src));
    float i2 = __builtin_amdgcn_rcpf(__shfl(acc11[r], src));
    int n = n0 + (r & 3) + 8 * ((r >> 2) & 3) + 4 * hi;
    float o0 = acc00[r] * i1 - acc10[r] * i2;   // d = l31 (0..31)
    float o1 = acc01[r] * i1 - acc11[r] * i2;   // d = 32 + l31 (valid < 48)
    int p0 = l31 >= 24;
    Ybh[p0 * 24576 + n * 24 + (l31 - p0 * 24)] = o0;
    if (l31 < 16) Ybh[24576 + n * 24 + 8 + l31] = o1;
  }
}

// ---------------- proj GEMM: proj_w(384x384) @ Y(384x1024) + b ----------------
__launch_bounds__(256)
__global__ void k_proj(const float* __restrict__ Y, const float* __restrict__ PW,
                       const float* __restrict__ PB, float* __restrict__ out) {
  const int tid = threadIdx.x, lane = tid & 63, wv = tid >> 6, l15 = lane & 15, g = lane >> 4;
  const int o0 = blockIdx.x * 64, m0 = blockIdx.y * 64, b = blockIdx.z;
  const float* Yb = Y + (long)b * 393216;
  floatx4 zero4 = {0.f, 0.f, 0.f, 0.f};
  floatx4 acc[4];
  #pragma unroll
  for (int i = 0; i < 4; i++) acc[i] = zero4;
  const int mcol = m0 + wv * 16 + l15;
  for (int c0 = 0; c0 < 384; c0 += 32) {
    half8 bfrag;
    const float* yp = Yb + (long)(c0 + g * 8) * 1024 + mcol;
    #pragma unroll
    for (int j = 0; j < 8; j++) bfrag[j] = (_Float16)yp[j * 1024];
    #pragma unroll
    for (int rt = 0; rt < 4; rt++) {
      const float* wp = PW + (o0 + rt * 16 + l15) * 384 + c0 + g * 8;
      floatx4 w0 = *(const floatx4*)wp;
      floatx4 w1 = *(const floatx4*)(wp + 4);
      half8 afrag;
      #pragma unroll
      for (int j = 0; j < 4; j++) { afrag[j] = (_Float16)w0[j]; afrag[j+4] = (_Float16)w1[j]; }
      acc[rt] = __builtin_amdgcn_mfma_f32_16x16x32_f16(afrag, bfrag, acc[rt], 0, 0, 0);
    }
  }
  #pragma unroll
  for (int rt = 0; rt < 4; rt++) {
    int o_ = o0 + rt * 16 + g * 4;
    #pragma unroll
    for (int r = 0; r < 4; r++) {
      out[(long)(b * 384 + o_ + r) * 1024 + mcol] = acc[rt][r] + PB[o_ + r];
    }
  }
}

extern "C" void kernel_launch(void* const* d_in, const int* in_sizes, int n_in,
                              void* d_out, int out_size, void* d_ws, size_t ws_size,
                              hipStream_t stream) {
  const float* x     = (const float*)d_in[0];
  const float* qkv_w = (const float*)d_in[1];
  const float* lam   = (const float*)d_in[2];
  const float* gw    = (const float*)d_in[3];
  const float* gb    = (const float*)d_in[4];
  const float* pw    = (const float*)d_in[5];
  const float* pb    = (const float*)d_in[6];
  float* out = (float*)d_out;
  char* ws = (char*)d_ws;
  _Float16* Q  = (_Float16*)ws;
  _Float16* Kt = (_Float16*)(ws + 8388608);
  _Float16* V  = (_Float16*)(ws + 16777216);
  float* Y       = (float*)(ws + 25165824);
  float* partial = (float*)(ws + 37748736);

  hipLaunchKernelGGL(k_init,    dim3(512),       dim3(256), 0, stream, Kt, V);
  hipLaunchKernelGGL(k_qkv,     dim3(24, 16, 8), dim3(256), 0, stream, x, qkv_w, Q, Kt, V);
  hipLaunchKernelGGL(k_gnstats, dim3(128),       dim3(256), 0, stream, Q, partial);
  hipLaunchKernelGGL(k_gnapply, dim3(256),       dim3(256), 0, stream, Q, partial, lam, gw, gb);
  hipLaunchKernelGGL(k_attn,    dim3(32, 8, 8),  dim3(64),  0, stream, Q, Kt, V, Y);
  hipLaunchKernelGGL(k_proj,    dim3(6, 16, 8),  dim3(256), 0, stream, Y, pw, pb, out);
}

// Round 5
// 208.409 us; speedup vs baseline: 1.3603x; 1.2288x over previous
//
#include <hip/hip_runtime.h>
#include <hip/hip_bf16.h>
#include <stdint.h>

typedef _Float16 half8 __attribute__((ext_vector_type(8)));
typedef _Float16 half4 __attribute__((ext_vector_type(4)));
typedef __fp16 fp16x2 __attribute__((ext_vector_type(2)));
typedef float floatx4 __attribute__((ext_vector_type(4)));
typedef float floatx16 __attribute__((ext_vector_type(16)));

#define SCALE 0.14433756729740643f
#define LOG2E 1.4426950408889634f

// ws layout (bytes):
// Q   f16 [8][8][1024][64]    off 0          cols: 0..23 q1, 24..31 zero, 32..55 q2, 56..63 zero
// K   f16 [8][8][1024][64]    off 8388608    same column layout
// V   f16 [8][8][64][1024]    off 16777216   rows 0..47 v, row 48 ones, 49..63 zero
// Y   f32 [8][384][1024]      off 25165824   scrambled pre-proj tensor
// partial f32 [128][2]        off 37748736
// Xt  f16 [8][12][1024][32]   off 37752832   transposed f16 x
// Yt  f16 [8][12][1024][32]   off 44044288   transposed f16 Y
// Wh  f16 [1152][384]         off 50335744
// PWh f16 [384][384]          off 51220480

__device__ inline float fexp2(float x) { return __builtin_exp2f(x); }

__device__ inline uint32_t pkrtz(float a, float b) {
  fp16x2 h = __builtin_amdgcn_cvt_pkrtz(a, b);
  union { fp16x2 h; uint32_t u; } cv; cv.h = h; return cv.u;
}

// V B-fragment load matching the natural P element order:
// element j <-> m-offset hi*4 + (j&3) + 8*(j>>2); p already points at +hi*4.
__device__ inline half8 ldv(const _Float16* p) {
  half4 a = *(const half4*)p;
  half4 b = *(const half4*)(p + 8);
  half8 r;
  r[0] = a[0]; r[1] = a[1]; r[2] = a[2]; r[3] = a[3];
  r[4] = b[0]; r[5] = b[1]; r[6] = b[2]; r[7] = b[3];
  return r;
}

// ---------------- init: K pad cols, V pad rows ----------------
__global__ void k_init(_Float16* __restrict__ Kt, _Float16* __restrict__ V) {
  int tid = blockIdx.x * 256 + threadIdx.x;
  half8 z = {(_Float16)0,(_Float16)0,(_Float16)0,(_Float16)0,(_Float16)0,(_Float16)0,(_Float16)0,(_Float16)0};
  if (tid < 65536) {
    _Float16* row = Kt + (long)tid * 64;
    *(half8*)(row + 24) = z;
    *(half8*)(row + 56) = z;
  } else {
    int t = tid - 65536;
    int bh = t >> 10, k = t & 1023;
    _Float16* p = V + (long)bh * 65536 + 49152 + k * 16;
    if (k < 64) {
      half8 one = {(_Float16)1,(_Float16)1,(_Float16)1,(_Float16)1,(_Float16)1,(_Float16)1,(_Float16)1,(_Float16)1};
      *(half8*)p = one; *(half8*)(p + 8) = one;
    } else {
      *(half8*)p = z; *(half8*)(p + 8) = z;
    }
  }
}

// ---------------- f32 -> f16 convert (contiguous) ----------------
__global__ void k_cvt(const float* __restrict__ src, _Float16* __restrict__ dst, int n) {
  int i = (blockIdx.x * 256 + threadIdx.x) * 8;
  if (i >= n) return;
  floatx4 a = *(const floatx4*)(src + i);
  floatx4 b = *(const floatx4*)(src + i + 4);
  half8 h;
  #pragma unroll
  for (int j = 0; j < 4; j++) { h[j] = (_Float16)a[j]; h[j+4] = (_Float16)b[j]; }
  *(half8*)(dst + i) = h;
}

// ---------------- transpose-convert: [384][1024] f32 -> [12][1024][32] f16 per b ----
__launch_bounds__(256)
__global__ void k_tr(const float* __restrict__ src, _Float16* __restrict__ dst) {
  const int cblk = blockIdx.x, nseg = blockIdx.y, b = blockIdx.z;
  const float* S = src + ((long)b * 384 + cblk * 32) * 1024 + nseg * 256;
  _Float16* D = dst + (long)b * 393216 + cblk * 32768 + (long)nseg * 256 * 32;
  __shared__ _Float16 T[32][264];
  const int wv = threadIdx.x >> 6, lane = threadIdx.x & 63;
  #pragma unroll
  for (int rr = 0; rr < 8; rr++) {
    int r = wv * 8 + rr;
    floatx4 v = *(const floatx4*)(S + (long)r * 1024 + lane * 4);
    half4 h;
    #pragma unroll
    for (int j = 0; j < 4; j++) h[j] = (_Float16)v[j];
    *(half4*)&T[r][lane * 4] = h;
  }
  __syncthreads();
  const int nn = threadIdx.x >> 3, c = (threadIdx.x & 7) * 4;
  #pragma unroll
  for (int p = 0; p < 8; p++) {
    int n = p * 32 + nn;
    half4 h;
    #pragma unroll
    for (int i = 0; i < 4; i++) h[i] = T[c + i][n];
    *(half4*)(D + (long)n * 32 + c) = h;
  }
}

// ---------------- QKV GEMM: Wh(1152x384) @ Xt per batch, f16 operands ----------------
__launch_bounds__(256)
__global__ void k_qkv(const _Float16* __restrict__ Xt, const _Float16* __restrict__ Wh,
                      _Float16* __restrict__ Q, _Float16* __restrict__ Kt,
                      _Float16* __restrict__ V) {
  const int tid = threadIdx.x;
  const int lane = tid & 63;
  const int wv = tid >> 6;
  const int l15 = lane & 15;
  const int g = lane >> 4;
  const int o0 = blockIdx.x * 48;
  const int n0 = blockIdx.y * 64;
  const int b = blockIdx.z;

  const int ncol = n0 + wv * 16 + l15;
  const _Float16* xp = Xt + (long)b * 393216 + (long)ncol * 32 + g * 8;
  const _Float16* wp = Wh + (long)(o0 + l15) * 384 + g * 8;

  floatx4 zero4 = {0.f, 0.f, 0.f, 0.f};
  floatx4 acc0 = zero4, acc1 = zero4, acc2 = zero4;

  half8 bf  = *(const half8*)xp;
  half8 af0 = *(const half8*)(wp);
  half8 af1 = *(const half8*)(wp + 6144);
  half8 af2 = *(const half8*)(wp + 12288);

  #pragma unroll
  for (int cb = 0; cb < 12; cb++) {
    half8 bc = bf, a0 = af0, a1 = af1, a2 = af2;
    if (cb < 11) {
      bf  = *(const half8*)(xp + (cb + 1) * 32768);
      af0 = *(const half8*)(wp + (cb + 1) * 32);
      af1 = *(const half8*)(wp + 6144 + (cb + 1) * 32);
      af2 = *(const half8*)(wp + 12288 + (cb + 1) * 32);
    }
    acc0 = __builtin_amdgcn_mfma_f32_16x16x32_f16(a0, bc, acc0, 0, 0, 0);
    acc1 = __builtin_amdgcn_mfma_f32_16x16x32_f16(a1, bc, acc1, 0, 0, 0);
    acc2 = __builtin_amdgcn_mfma_f32_16x16x32_f16(a2, bc, acc2, 0, 0, 0);
  }

  floatx4 acc[3] = {acc0, acc1, acc2};
  __shared__ __align__(16) _Float16 T[3456];   // max(64*52, 48*72)

  if (o0 < 768) {
    // q or k rows: dump transposed T[n(64)][o(48), stride 52]
    #pragma unroll
    for (int rt = 0; rt < 3; rt++)
      #pragma unroll
      for (int r = 0; r < 4; r++)
        T[(wv * 16 + l15) * 52 + rt * 16 + g * 4 + r] = (_Float16)acc[rt][r];
    __syncthreads();
    if (tid < 128) {
      int n_ = tid >> 1, part = tid & 1;
      int qk = o0 >= 384;
      int hh = (o0 - qk * 384) / 48;
      _Float16* dst = (qk ? Kt : Q) + ((long)((b * 8 + hh) * 1024 + n0 + n_)) * 64 + part * 32;
      const _Float16* src = T + n_ * 52 + part * 24;
      uint32_t buf[12];
      #pragma unroll
      for (int i = 0; i < 12; i++) {
        union { _Float16 h[2]; uint32_t u; } cv;
        cv.h[0] = src[2*i]; cv.h[1] = src[2*i+1];
        buf[i] = cv.u;
      }
      #pragma unroll
      for (int i = 0; i < 3; i++) {
        uint4 v; v.x = buf[4*i]; v.y = buf[4*i+1]; v.z = buf[4*i+2]; v.w = buf[4*i+3];
        ((uint4*)dst)[i] = v;
      }
    }
  } else {
    // v rows: natural dump T[o(48)][n(64), stride 72]
    #pragma unroll
    for (int rt = 0; rt < 3; rt++)
      #pragma unroll
      for (int r = 0; r < 4; r++)
        T[(rt * 16 + g * 4 + r) * 72 + wv * 16 + l15] = (_Float16)acc[rt][r];
    __syncthreads();
    if (tid < 192) {
      int row = tid >> 2, seg = tid & 3;
      int oo = o0 - 768 + row;
      int hh = oo / 48, d48 = oo % 48;
      _Float16* dst = V + ((long)((b * 8 + hh) * 64 + d48)) * 1024 + n0 + seg * 16;
      half8 v0 = *(const half8*)(T + row * 72 + seg * 16);
      half8 v1 = *(const half8*)(T + row * 72 + seg * 16 + 8);
      *(half8*)dst = v0;
      *(half8*)(dst + 8) = v1;
    }
  }
}

// ---------------- GroupNorm stats (deterministic chunked partials) ----------------
__global__ void k_gnstats(const _Float16* __restrict__ Q, float* __restrict__ partial) {
  int bg = blockIdx.x >> 3;
  int chunk = blockIdx.x & 7;
  int b = bg >> 1, grp = bg & 1;
  float s1 = 0.f, s2 = 0.f;
  for (int rr = chunk * 512 + threadIdx.x; rr < chunk * 512 + 512; rr += 256) {
    int h = grp * 4 + (rr >> 10);
    int n = rr & 1023;
    const _Float16* p = Q + ((long)((b * 8 + h) * 1024 + n)) * 64 + 32;
    #pragma unroll
    for (int s = 0; s < 3; s++) {
      half8 v = *(const half8*)(p + s * 8);
      #pragma unroll
      for (int j = 0; j < 8; j++) { float f = (float)v[j]; s1 += f; s2 += f * f; }
    }
  }
  #pragma unroll
  for (int off = 32; off > 0; off >>= 1) {
    s1 += __shfl_down(s1, off);
    s2 += __shfl_down(s2, off);
  }
  __shared__ float red[8];
  int wv = threadIdx.x >> 6;
  if ((threadIdx.x & 63) == 0) { red[wv] = s1; red[4 + wv] = s2; }
  __syncthreads();
  if (threadIdx.x == 0) {
    float S1 = red[0] + red[1] + red[2] + red[3];
    float S2 = red[4] + red[5] + red[6] + red[7];
    partial[blockIdx.x * 2]     = S1;
    partial[blockIdx.x * 2 + 1] = S2;
  }
}

// ---------------- GN apply + fold scale*log2e into Q, write zero pads ----------------
__global__ void k_gnapply(_Float16* __restrict__ Q, const float* __restrict__ partial,
                          const float* __restrict__ lam, const float* __restrict__ gw,
                          const float* __restrict__ gb) {
  int r = blockIdx.x * 256 + threadIdx.x;
  int h = (r >> 10) & 7;
  int grp = h >> 2;
  int b = r >> 13;
  const float* pp = partial + (b * 2 + grp) * 16;
  float S1 = 0.f, S2 = 0.f;
  #pragma unroll
  for (int i = 0; i < 8; i++) { S1 += pp[2*i]; S2 += pp[2*i+1]; }
  float mean = S1 * (1.f / 98304.f);
  float rstd = rsqrtf(S2 * (1.f / 98304.f) - mean * mean + 1e-5f);
  const float s1s = SCALE * LOG2E;
  float sl = s1s * lam[h];
  _Float16* row = Q + (long)r * 64;
  half8 z = {(_Float16)0,(_Float16)0,(_Float16)0,(_Float16)0,(_Float16)0,(_Float16)0,(_Float16)0,(_Float16)0};
  #pragma unroll
  for (int s = 0; s < 3; s++) {
    half8 v = *(half8*)(row + s * 8);
    #pragma unroll
    for (int j = 0; j < 8; j++) v[j] = (_Float16)((float)v[j] * s1s);
    *(half8*)(row + s * 8) = v;
  }
  *(half8*)(row + 24) = z;
  #pragma unroll
  for (int s = 0; s < 3; s++) {
    half8 v = *(half8*)(row + 32 + s * 8);
    #pragma unroll
    for (int j = 0; j < 8; j++) {
      int c = s * 8 + j;
      v[j] = (_Float16)((((float)v[j] - mean) * rstd * gw[h * 24 + c] + gb[h * 24 + c]) * sl);
    }
    *(half8*)(row + 32 + s * 8) = v;
  }
  *(half8*)(row + 56) = z;
}

// ---------------- fused dual-softmax attention: barrier-free, 1 wave / 32 q-rows ----
// XCD-swizzled 1D grid: id&7 keeps all 32 n-tiles of one (b,h) on one XCD so
// K/V (256KB/head) stay L2-resident. Compute identical to round-4 version.
__launch_bounds__(64, 2)
__global__ void k_attn(const _Float16* __restrict__ Q, const _Float16* __restrict__ K,
                       const _Float16* __restrict__ V, float* __restrict__ Y) {
  const int lane = threadIdx.x;
  const int l31 = lane & 31;
  const int hi = lane >> 5;
  const int id = blockIdx.x;
  const int p = (id >> 8) * 8 + (id & 7);   // (b*8+h), 32 consecutive tiles per XCD slot
  const int n0 = ((id >> 3) & 31) * 32;
  const int b = p >> 3, h = p & 7;

  const _Float16* Qbh = Q + (long)(b * 8 + h) * 65536;
  const _Float16* Kbh = K + (long)(b * 8 + h) * 65536;
  const _Float16* Vbh = V + (long)(b * 8 + h) * 65536;

  const _Float16* qp = Qbh + (n0 + l31) * 64 + hi * 8;
  half8 qf0 = *(const half8*)(qp);
  half8 qf1 = *(const half8*)(qp + 16);
  half8 qf2 = *(const half8*)(qp + 32);
  half8 qf3 = *(const half8*)(qp + 48);

  floatx16 z16;
  #pragma unroll
  for (int i = 0; i < 16; i++) z16[i] = 0.f;
  floatx16 acc00 = z16, acc01 = z16, acc10 = z16, acc11 = z16;

  #pragma unroll 2
  for (int m0 = 0; m0 < 1024; m0 += 32) {
    const _Float16* kp = Kbh + (m0 + l31) * 64 + hi * 8;
    half8 kf0 = *(const half8*)(kp);
    half8 kf1 = *(const half8*)(kp + 16);
    half8 kf2 = *(const half8*)(kp + 32);
    half8 kf3 = *(const half8*)(kp + 48);

    floatx16 s1 = __builtin_amdgcn_mfma_f32_32x32x16_f16(kf0, qf0, z16, 0, 0, 0);
    s1 = __builtin_amdgcn_mfma_f32_32x32x16_f16(kf1, qf1, s1, 0, 0, 0);
    floatx16 s2 = __builtin_amdgcn_mfma_f32_32x32x16_f16(kf2, qf2, z16, 0, 0, 0);
    s2 = __builtin_amdgcn_mfma_f32_32x32x16_f16(kf3, qf3, s2, 0, 0, 0);

    const _Float16* vp = Vbh + l31 * 1024 + m0 + hi * 4;
    half8 vf00 = ldv(vp);
    half8 vf01 = ldv(vp + 16);
    half8 vf10 = ldv(vp + 32768);
    half8 vf11 = ldv(vp + 32768 + 16);

    uint32_t u1[8], u2[8];
    #pragma unroll
    for (int q = 0; q < 8; q++) {
      u1[q] = pkrtz(fexp2(s1[2 * q]), fexp2(s1[2 * q + 1]));
      u2[q] = pkrtz(fexp2(s2[2 * q]), fexp2(s2[2 * q + 1]));
    }

    union { uint32_t u[4]; half8 h; } pa;
    pa.u[0] = u1[0]; pa.u[1] = u1[1]; pa.u[2] = u1[2]; pa.u[3] = u1[3];
    half8 p1c0 = pa.h;
    pa.u[0] = u1[4]; pa.u[1] = u1[5]; pa.u[2] = u1[6]; pa.u[3] = u1[7];
    half8 p1c1 = pa.h;
    pa.u[0] = u2[0]; pa.u[1] = u2[1]; pa.u[2] = u2[2]; pa.u[3] = u2[3];
    half8 p2c0 = pa.h;
    pa.u[0] = u2[4]; pa.u[1] = u2[5]; pa.u[2] = u2[6]; pa.u[3] = u2[7];
    half8 p2c1 = pa.h;

    acc00 = __builtin_amdgcn_mfma_f32_32x32x16_f16(p1c0, vf00, acc00, 0, 0, 0);
    acc00 = __builtin_amdgcn_mfma_f32_32x32x16_f16(p1c1, vf01, acc00, 0, 0, 0);
    acc01 = __builtin_amdgcn_mfma_f32_32x32x16_f16(p1c0, vf10, acc01, 0, 0, 0);
    acc01 = __builtin_amdgcn_mfma_f32_32x32x16_f16(p1c1, vf11, acc01, 0, 0, 0);
    acc10 = __builtin_amdgcn_mfma_f32_32x32x16_f16(p2c0, vf00, acc10, 0, 0, 0);
    acc10 = __builtin_amdgcn_mfma_f32_32x32x16_f16(p2c1, vf01, acc10, 0, 0, 0);
    acc11 = __builtin_amdgcn_mfma_f32_32x32x16_f16(p2c0, vf10, acc11, 0, 0, 0);
    acc11 = __builtin_amdgcn_mfma_f32_32x32x16_f16(p2c1, vf11, acc11, 0, 0, 0);
  }

  float* Ybh = Y + (long)(b * 8 + h) * 49152;
  const int src = (lane & 32) + 16;
  #pragma unroll
  for (int r = 0; r < 16; r++) {
    float i1 = __builtin_amdgcn_rcpf(__shfl(acc01[r], src));
    float i2 = __builtin_amdgcn_rcpf(__shfl(acc11[r], src));
    int n = n0 + (r & 3) + 8 * ((r >> 2) & 3) + 4 * hi;
    float o0 = acc00[r] * i1 - acc10[r] * i2;
    float o1 = acc01[r] * i1 - acc11[r] * i2;
    int p0 = l31 >= 24;
    Ybh[p0 * 24576 + n * 24 + (l31 - p0 * 24)] = o0;
    if (l31 < 16) Ybh[24576 + n * 24 + 8 + l31] = o1;
  }
}

// ---------------- proj GEMM: PWh(384x384) @ Yt + b, f16 operands ----------------
__launch_bounds__(256)
__global__ void k_proj(const _Float16* __restrict__ Yt, const _Float16* __restrict__ PWh,
                       const float* __restrict__ PB, float* __restrict__ out) {
  const int tid = threadIdx.x, lane = tid & 63, wv = tid >> 6, l15 = lane & 15, g = lane >> 4;
  const int o0 = blockIdx.x * 64, m0 = blockIdx.y * 64, b = blockIdx.z;

  const int mcol = m0 + wv * 16 + l15;
  const _Float16* yp = Yt + (long)b * 393216 + (long)mcol * 32 + g * 8;
  const _Float16* wp = PWh + (long)(o0 + l15) * 384 + g * 8;

  floatx4 zero4 = {0.f, 0.f, 0.f, 0.f};
  floatx4 acc0 = zero4, acc1 = zero4, acc2 = zero4, acc3 = zero4;

  half8 bf  = *(const half8*)yp;
  half8 af0 = *(const half8*)(wp);
  half8 af1 = *(const half8*)(wp + 6144);
  half8 af2 = *(const half8*)(wp + 12288);
  half8 af3 = *(const half8*)(wp + 18432);

  #pragma unroll
  for (int cb = 0; cb < 12; cb++) {
    half8 bc = bf, a0 = af0, a1 = af1, a2 = af2, a3 = af3;
    if (cb < 11) {
      bf  = *(const half8*)(yp + (cb + 1) * 32768);
      af0 = *(const half8*)(wp + (cb + 1) * 32);
      af1 = *(const half8*)(wp + 6144 + (cb + 1) * 32);
      af2 = *(const half8*)(wp + 12288 + (cb + 1) * 32);
      af3 = *(const half8*)(wp + 18432 + (cb + 1) * 32);
    }
    acc0 = __builtin_amdgcn_mfma_f32_16x16x32_f16(a0, bc, acc0, 0, 0, 0);
    acc1 = __builtin_amdgcn_mfma_f32_16x16x32_f16(a1, bc, acc1, 0, 0, 0);
    acc2 = __builtin_amdgcn_mfma_f32_16x16x32_f16(a2, bc, acc2, 0, 0, 0);
    acc3 = __builtin_amdgcn_mfma_f32_16x16x32_f16(a3, bc, acc3, 0, 0, 0);
  }

  floatx4 acc[4] = {acc0, acc1, acc2, acc3};
  #pragma unroll
  for (int rt = 0; rt < 4; rt++) {
    int o_ = o0 + rt * 16 + g * 4;
    #pragma unroll
    for (int r = 0; r < 4; r++) {
      out[(long)(b * 384 + o_ + r) * 1024 + mcol] = acc[rt][r] + PB[o_ + r];
    }
  }
}

extern "C" void kernel_launch(void* const* d_in, const int* in_sizes, int n_in,
                              void* d_out, int out_size, void* d_ws, size_t ws_size,
                              hipStream_t stream) {
  const float* x     = (const float*)d_in[0];
  const float* qkv_w = (const float*)d_in[1];
  const float* lam   = (const float*)d_in[2];
  const float* gw    = (const float*)d_in[3];
  const float* gb    = (const float*)d_in[4];
  const float* pw    = (const float*)d_in[5];
  const float* pb    = (const float*)d_in[6];
  float* out = (float*)d_out;
  char* ws = (char*)d_ws;
  _Float16* Q   = (_Float16*)ws;
  _Float16* Kt  = (_Float16*)(ws + 8388608);
  _Float16* V   = (_Float16*)(ws + 16777216);
  float* Y        = (float*)(ws + 25165824);
  float* partial  = (float*)(ws + 37748736);
  _Float16* Xt  = (_Float16*)(ws + 37752832);
  _Float16* Yt  = (_Float16*)(ws + 44044288);
  _Float16* Wh  = (_Float16*)(ws + 50335744);
  _Float16* PWh = (_Float16*)(ws + 51220480);

  hipLaunchKernelGGL(k_init,    dim3(512),        dim3(256), 0, stream, Kt, V);
  hipLaunchKernelGGL(k_cvt,     dim3(216),        dim3(256), 0, stream, qkv_w, Wh, 442368);
  hipLaunchKernelGGL(k_cvt,     dim3(72),         dim3(256), 0, stream, pw, PWh, 147456);
  hipLaunchKernelGGL(k_tr,      dim3(12, 4, 8),   dim3(256), 0, stream, x, Xt);
  hipLaunchKernelGGL(k_qkv,     dim3(24, 16, 8),  dim3(256), 0, stream, Xt, Wh, Q, Kt, V);
  hipLaunchKernelGGL(k_gnstats, dim3(128),        dim3(256), 0, stream, Q, partial);
  hipLaunchKernelGGL(k_gnapply, dim3(256),        dim3(256), 0, stream, Q, partial, lam, gw, gb);
  hipLaunchKernelGGL(k_attn,    dim3(2048),       dim3(64),  0, stream, Q, Kt, V, Y);
  hipLaunchKernelGGL(k_tr,      dim3(12, 4, 8),   dim3(256), 0, stream, Y, Yt);
  hipLaunchKernelGGL(k_proj,    dim3(6, 16, 8),   dim3(256), 0, stream, Yt, PWh, pb, out);
}

// Round 6
// 166.137 us; speedup vs baseline: 1.7064x; 1.2544x over previous
//
#include <hip/hip_runtime.h>
#include <hip/hip_bf16.h>
#include <stdint.h>

typedef _Float16 half8 __attribute__((ext_vector_type(8)));
typedef _Float16 half4 __attribute__((ext_vector_type(4)));
typedef __fp16 fp16x2 __attribute__((ext_vector_type(2)));
typedef float floatx4 __attribute__((ext_vector_type(4)));
typedef float floatx16 __attribute__((ext_vector_type(16)));

#define SCALE 0.14433756729740643f
#define LOG2E 1.4426950408889634f

// ws layout (bytes):
// Qswz f16 [64bh][32ntile][4t][64lane][8]  off 0         (8 MB) fragment-major Q
// Kswz f16 [64bh][32win][4t][64lane][8]    off 8388608   (8 MB) fragment-major K
// Vswz f16 [64bh][32win][2c][2kc][64][8]   off 16777216  (8 MB) fragment-major V
// Y    f32 [8][384][1024]                  off 25165824  scrambled pre-proj tensor
// partial f32 [128][2]                     off 37748736
// Xt   f16 [8][12][1024][32]               off 37752832
// Yt   f16 [8][12][1024][32]               off 44044288
// Wh   f16 [1152][384]                     off 50335744
// PWh  f16 [384][384]                      off 51220480
//
// Q/K logical cols (64): 0..23 q1, 24..31 zero, 32..55 q2, 56..63 zero.
// col <-> (t,hi,j): col = t*16 + hi*8 + j ; slot lane = hi*32 + l31(row).
// V logical rows (64): 0..47 v, 48 ones, 49..63 zero; element j <-> m-offset
// kc*16 + hi*4 + (j&3) + 8*(j>>2).

__device__ inline float fexp2(float x) { return __builtin_exp2f(x); }

__device__ inline uint32_t pkrtz(float a, float b) {
  fp16x2 h = __builtin_amdgcn_cvt_pkrtz(a, b);
  union { fp16x2 h; uint32_t u; } cv; cv.h = h; return cv.u;
}

// ---------------- f32 -> f16 convert (contiguous) ----------------
__global__ void k_cvt(const float* __restrict__ src, _Float16* __restrict__ dst, int n) {
  int i = (blockIdx.x * 256 + threadIdx.x) * 8;
  if (i >= n) return;
  floatx4 a = *(const floatx4*)(src + i);
  floatx4 b = *(const floatx4*)(src + i + 4);
  half8 h;
  #pragma unroll
  for (int j = 0; j < 4; j++) { h[j] = (_Float16)a[j]; h[j+4] = (_Float16)b[j]; }
  *(half8*)(dst + i) = h;
}

// ---------------- transpose-convert: [384][1024] f32 -> [12][1024][32] f16 per b ----
__launch_bounds__(256)
__global__ void k_tr(const float* __restrict__ src, _Float16* __restrict__ dst) {
  const int cblk = blockIdx.x, nseg = blockIdx.y, b = blockIdx.z;
  const float* S = src + ((long)b * 384 + cblk * 32) * 1024 + nseg * 256;
  _Float16* D = dst + (long)b * 393216 + cblk * 32768 + (long)nseg * 256 * 32;
  __shared__ _Float16 T[32][264];
  const int wv = threadIdx.x >> 6, lane = threadIdx.x & 63;
  #pragma unroll
  for (int rr = 0; rr < 8; rr++) {
    int r = wv * 8 + rr;
    floatx4 v = *(const floatx4*)(S + (long)r * 1024 + lane * 4);
    half4 h;
    #pragma unroll
    for (int j = 0; j < 4; j++) h[j] = (_Float16)v[j];
    *(half4*)&T[r][lane * 4] = h;
  }
  __syncthreads();
  const int nn = threadIdx.x >> 3, c = (threadIdx.x & 7) * 4;
  #pragma unroll
  for (int p = 0; p < 8; p++) {
    int n = p * 32 + nn;
    half4 h;
    #pragma unroll
    for (int i = 0; i < 4; i++) h[i] = T[c + i][n];
    *(half4*)(D + (long)n * 32 + c) = h;
  }
}

// ---------------- QKV GEMM: Wh(1152x384) @ Xt per batch -> swizzled Q/K/V ----------
__launch_bounds__(256)
__global__ void k_qkv(const _Float16* __restrict__ Xt, const _Float16* __restrict__ Wh,
                      _Float16* __restrict__ Qs, _Float16* __restrict__ Ks,
                      _Float16* __restrict__ Vs) {
  const int tid = threadIdx.x;
  const int lane = tid & 63;
  const int wv = tid >> 6;
  const int l15 = lane & 15;
  const int g = lane >> 4;
  const int o0 = blockIdx.x * 48;
  const int n0 = blockIdx.y * 64;
  const int b = blockIdx.z;

  const int ncol = n0 + wv * 16 + l15;
  const _Float16* xp = Xt + (long)b * 393216 + (long)ncol * 32 + g * 8;
  const _Float16* wp = Wh + (long)(o0 + l15) * 384 + g * 8;

  floatx4 zero4 = {0.f, 0.f, 0.f, 0.f};
  floatx4 acc0 = zero4, acc1 = zero4, acc2 = zero4;

  half8 bf  = *(const half8*)xp;
  half8 af0 = *(const half8*)(wp);
  half8 af1 = *(const half8*)(wp + 6144);
  half8 af2 = *(const half8*)(wp + 12288);

  #pragma unroll
  for (int cb = 0; cb < 12; cb++) {
    half8 bc = bf, a0 = af0, a1 = af1, a2 = af2;
    if (cb < 11) {
      bf  = *(const half8*)(xp + (cb + 1) * 32768);
      af0 = *(const half8*)(wp + (cb + 1) * 32);
      af1 = *(const half8*)(wp + 6144 + (cb + 1) * 32);
      af2 = *(const half8*)(wp + 12288 + (cb + 1) * 32);
    }
    acc0 = __builtin_amdgcn_mfma_f32_16x16x32_f16(a0, bc, acc0, 0, 0, 0);
    acc1 = __builtin_amdgcn_mfma_f32_16x16x32_f16(a1, bc, acc1, 0, 0, 0);
    acc2 = __builtin_amdgcn_mfma_f32_16x16x32_f16(a2, bc, acc2, 0, 0, 0);
  }

  floatx4 acc[3] = {acc0, acc1, acc2};
  __shared__ __align__(16) _Float16 T[3456];   // max(64*52, 48*72)

  if (o0 < 768) {
    // q or k rows: dump transposed T[n(64)][o48, stride 52]
    #pragma unroll
    for (int rt = 0; rt < 3; rt++)
      #pragma unroll
      for (int r = 0; r < 4; r++)
        T[(wv * 16 + l15) * 52 + rt * 16 + g * 4 + r] = (_Float16)acc[rt][r];
    __syncthreads();
    const int qk = o0 >= 384;
    const int hh = (o0 - qk * 384) / 48;
    _Float16* base = (qk ? Ks : Qs) + (long)(b * 8 + hh) * 65536;
    #pragma unroll
    for (int it = 0; it < 2; it++) {
      int slot = it * 256 + tid;          // (ntl, t, ln)
      int ntl = slot >> 8;
      int t   = (slot >> 6) & 3;
      int ln  = slot & 63;
      int hi_s = ln >> 5, l31_s = ln & 31;
      int n_ = ntl * 32 + l31_s;
      int c0 = t * 16 + hi_s * 8;
      half8 val;
      #pragma unroll
      for (int j = 0; j < 8; j++) {
        int col = c0 + j;
        int d48 = col < 24 ? col : col - 8;
        bool isq = (col < 24) || (col >= 32 && col < 56);
        val[j] = isq ? T[n_ * 52 + d48] : (_Float16)0;
      }
      *(half8*)(base + ((((n0 >> 5) + ntl) * 4 + t) * 64 + ln) * 8) = val;
    }
  } else {
    // v rows: natural dump T[o48][n(64), stride 72]
    #pragma unroll
    for (int rt = 0; rt < 3; rt++)
      #pragma unroll
      for (int r = 0; r < 4; r++)
        T[(rt * 16 + g * 4 + r) * 72 + wv * 16 + l15] = (_Float16)acc[rt][r];
    __syncthreads();
    const int hh = (o0 - 768) / 48;
    _Float16* base = Vs + (long)(b * 8 + hh) * 65536;
    #pragma unroll
    for (int it = 0; it < 2; it++) {
      int slot = it * 256 + tid;          // (lwin, ckc, ln)
      int lwin = slot >> 8;
      int ckc  = (slot >> 6) & 3;
      int kc   = ckc & 1, c = ckc >> 1;
      int ln = slot & 63;
      int hi_s = ln >> 5, l31_s = ln & 31;
      int d48 = c * 32 + l31_s;
      half8 val;
      if (d48 < 48) {
        int mb = lwin * 32 + kc * 16 + hi_s * 4;
        half4 a = *(const half4*)&T[d48 * 72 + mb];
        half4 bq = *(const half4*)&T[d48 * 72 + mb + 8];
        val[0] = a[0]; val[1] = a[1]; val[2] = a[2]; val[3] = a[3];
        val[4] = bq[0]; val[5] = bq[1]; val[6] = bq[2]; val[7] = bq[3];
      } else {
        _Float16 f = (d48 == 48) ? (_Float16)1 : (_Float16)0;
        #pragma unroll
        for (int j = 0; j < 8; j++) val[j] = f;
      }
      *(half8*)(base + ((((n0 >> 5) + lwin) * 4 + ckc) * 64 + ln) * 8) = val;
    }
  }
}

// ---------------- GroupNorm stats over swizzled q2 (deterministic partials) -------
__global__ void k_gnstats(const _Float16* __restrict__ Qs, float* __restrict__ partial) {
  int bg = blockIdx.x >> 3;
  int chunk = blockIdx.x & 7;
  int b = bg >> 1, grp = bg & 1;
  float s1 = 0.f, s2 = 0.f;
  #pragma unroll
  for (int k = 0; k < 6; k++) {
    int f = chunk * 1536 + k * 256 + threadIdx.x;
    int uid = f / 96;            // (h4, ntile32) unit within (b,grp)
    int slot = f - uid * 96;     // 0..63 -> t2 ; 64..95 -> t3 lanes 0..31
    int h = grp * 4 + (uid >> 5);
    int ntile = uid & 31;
    int t = slot < 64 ? 2 : 3;
    int ln = slot < 64 ? slot : slot - 64;
    const _Float16* p = Qs + (long)(b * 8 + h) * 65536 + ((ntile * 4 + t) * 64 + ln) * 8;
    half8 v = *(const half8*)p;
    #pragma unroll
    for (int j = 0; j < 8; j++) { float x = (float)v[j]; s1 += x; s2 += x * x; }
  }
  #pragma unroll
  for (int off = 32; off > 0; off >>= 1) {
    s1 += __shfl_down(s1, off);
    s2 += __shfl_down(s2, off);
  }
  __shared__ float red[8];
  int wv = threadIdx.x >> 6;
  if ((threadIdx.x & 63) == 0) { red[wv] = s1; red[4 + wv] = s2; }
  __syncthreads();
  if (threadIdx.x == 0) {
    float S1 = red[0] + red[1] + red[2] + red[3];
    float S2 = red[4] + red[5] + red[6] + red[7];
    partial[blockIdx.x * 2]     = S1;
    partial[blockIdx.x * 2 + 1] = S2;
  }
}

// ---------------- GN apply + fold scale*log2e, on swizzled Q ----------------
__global__ void k_gnapply(_Float16* __restrict__ Qs, const float* __restrict__ partial,
                          const float* __restrict__ lam, const float* __restrict__ gw,
                          const float* __restrict__ gb) {
  int G = blockIdx.x * 256 + threadIdx.x;   // 393216 chunks of 8 halves
  int g = G / 192;
  int r = G - g * 192;
  int bh = g >> 5, ntile = g & 31;
  int b = bh >> 3, h = bh & 7, grp = h >> 2;
  const float* pp = partial + (b * 2 + grp) * 16;
  float S1 = 0.f, S2 = 0.f;
  #pragma unroll
  for (int i = 0; i < 8; i++) { S1 += pp[2*i]; S2 += pp[2*i+1]; }
  float mean = S1 * (1.f / 98304.f);
  float rstd = rsqrtf(S2 * (1.f / 98304.f) - mean * mean + 1e-5f);
  const float s1s = SCALE * LOG2E;
  float sl = s1s * lam[h];
  int t, ln;
  if (r < 64)       { t = 0; ln = r; }
  else if (r < 96)  { t = 1; ln = r - 64; }
  else if (r < 160) { t = 2; ln = r - 96; }
  else              { t = 3; ln = r - 160; }
  int hi = ln >> 5;
  _Float16* p = Qs + (long)bh * 65536 + ((ntile * 4 + t) * 64 + ln) * 8;
  half8 v = *(half8*)p;
  if (t < 2) {
    #pragma unroll
    for (int j = 0; j < 8; j++) v[j] = (_Float16)((float)v[j] * s1s);
  } else {
    int cbase = (t == 2) ? hi * 8 : 16;
    #pragma unroll
    for (int j = 0; j < 8; j++) {
      int c = cbase + j;
      v[j] = (_Float16)((((float)v[j] - mean) * rstd * gw[h * 24 + c] + gb[h * 24 + c]) * sl);
    }
  }
  *(half8*)p = v;
}

// ---------------- fused dual-softmax attention: barrier-free, coalesced frags ----
// All Q/K/V reads are base + lane*16B (fragment-major layouts) -> 1KB coalesced
// b128 per instruction. Compute identical to round-4/5 (numerics preserved).
__launch_bounds__(64, 2)
__global__ void k_attn(const _Float16* __restrict__ Qs, const _Float16* __restrict__ Ks,
                       const _Float16* __restrict__ Vs, float* __restrict__ Y) {
  const int lane = threadIdx.x;
  const int l31 = lane & 31;
  const int hi = lane >> 5;
  const int id = blockIdx.x;
  const int p = (id >> 8) * 8 + (id & 7);   // (b*8+h): keeps one head per XCD slot
  const int ntile = (id >> 3) & 31;
  const int n0 = ntile * 32;
  const int b = p >> 3, h = p & 7;
  const long bh = b * 8 + h;

  const _Float16* Qp = Qs + bh * 65536 + (ntile * 256 + lane) * 8;
  const _Float16* Kp = Ks + bh * 65536 + lane * 8;
  const _Float16* Vp = Vs + bh * 65536 + lane * 8;

  half8 qf0 = *(const half8*)(Qp);
  half8 qf1 = *(const half8*)(Qp + 512);
  half8 qf2 = *(const half8*)(Qp + 1024);
  half8 qf3 = *(const half8*)(Qp + 1536);

  floatx16 z16;
  #pragma unroll
  for (int i = 0; i < 16; i++) z16[i] = 0.f;
  floatx16 acc00 = z16, acc01 = z16, acc10 = z16, acc11 = z16;

  #pragma unroll 2
  for (int w = 0; w < 32; w++) {
    const _Float16* kp = Kp + w * 2048;
    half8 kf0 = *(const half8*)(kp);
    half8 kf1 = *(const half8*)(kp + 512);
    half8 kf2 = *(const half8*)(kp + 1024);
    half8 kf3 = *(const half8*)(kp + 1536);

    floatx16 s1 = __builtin_amdgcn_mfma_f32_32x32x16_f16(kf0, qf0, z16, 0, 0, 0);
    s1 = __builtin_amdgcn_mfma_f32_32x32x16_f16(kf1, qf1, s1, 0, 0, 0);
    floatx16 s2 = __builtin_amdgcn_mfma_f32_32x32x16_f16(kf2, qf2, z16, 0, 0, 0);
    s2 = __builtin_amdgcn_mfma_f32_32x32x16_f16(kf3, qf3, s2, 0, 0, 0);

    const _Float16* vp = Vp + w * 2048;
    half8 vf00 = *(const half8*)(vp);            // c0,kc0
    half8 vf01 = *(const half8*)(vp + 512);      // c0,kc1
    half8 vf10 = *(const half8*)(vp + 1024);     // c1,kc0
    half8 vf11 = *(const half8*)(vp + 1536);     // c1,kc1

    uint32_t u1[8], u2[8];
    #pragma unroll
    for (int q = 0; q < 8; q++) {
      u1[q] = pkrtz(fexp2(s1[2 * q]), fexp2(s1[2 * q + 1]));
      u2[q] = pkrtz(fexp2(s2[2 * q]), fexp2(s2[2 * q + 1]));
    }

    union { uint32_t u[4]; half8 h; } pa;
    pa.u[0] = u1[0]; pa.u[1] = u1[1]; pa.u[2] = u1[2]; pa.u[3] = u1[3];
    half8 p1c0 = pa.h;
    pa.u[0] = u1[4]; pa.u[1] = u1[5]; pa.u[2] = u1[6]; pa.u[3] = u1[7];
    half8 p1c1 = pa.h;
    pa.u[0] = u2[0]; pa.u[1] = u2[1]; pa.u[2] = u2[2]; pa.u[3] = u2[3];
    half8 p2c0 = pa.h;
    pa.u[0] = u2[4]; pa.u[1] = u2[5]; pa.u[2] = u2[6]; pa.u[3] = u2[7];
    half8 p2c1 = pa.h;

    acc00 = __builtin_amdgcn_mfma_f32_32x32x16_f16(p1c0, vf00, acc00, 0, 0, 0);
    acc00 = __builtin_amdgcn_mfma_f32_32x32x16_f16(p1c1, vf01, acc00, 0, 0, 0);
    acc01 = __builtin_amdgcn_mfma_f32_32x32x16_f16(p1c0, vf10, acc01, 0, 0, 0);
    acc01 = __builtin_amdgcn_mfma_f32_32x32x16_f16(p1c1, vf11, acc01, 0, 0, 0);
    acc10 = __builtin_amdgcn_mfma_f32_32x32x16_f16(p2c0, vf00, acc10, 0, 0, 0);
    acc10 = __builtin_amdgcn_mfma_f32_32x32x16_f16(p2c1, vf01, acc10, 0, 0, 0);
    acc11 = __builtin_amdgcn_mfma_f32_32x32x16_f16(p2c0, vf10, acc11, 0, 0, 0);
    acc11 = __builtin_amdgcn_mfma_f32_32x32x16_f16(p2c1, vf11, acc11, 0, 0, 0);
  }

  float* Ybh = Y + bh * 49152;
  const int src = (lane & 32) + 16;
  #pragma unroll
  for (int r = 0; r < 16; r++) {
    float i1 = __builtin_amdgcn_rcpf(__shfl(acc01[r], src));
    float i2 = __builtin_amdgcn_rcpf(__shfl(acc11[r], src));
    int n = n0 + (r & 3) + 8 * ((r >> 2) & 3) + 4 * hi;
    float o0 = acc00[r] * i1 - acc10[r] * i2;
    float o1 = acc01[r] * i1 - acc11[r] * i2;
    int p0 = l31 >= 24;
    Ybh[p0 * 24576 + n * 24 + (l31 - p0 * 24)] = o0;
    if (l31 < 16) Ybh[24576 + n * 24 + 8 + l31] = o1;
  }
}

// ---------------- proj GEMM: PWh(384x384) @ Yt + b ----------------
__launch_bounds__(256)
__global__ void k_proj(const _Float16* __restrict__ Yt, const _Float16* __restrict__ PWh,
                       const float* __restrict__ PB, float* __restrict__ out) {
  const int tid = threadIdx.x, lane = tid & 63, wv = tid >> 6, l15 = lane & 15, g = lane >> 4;
  const int o0 = blockIdx.x * 64, m0 = blockIdx.y * 64, b = blockIdx.z;

  const int mcol = m0 + wv * 16 + l15;
  const _Float16* yp = Yt + (long)b * 393216 + (long)mcol * 32 + g * 8;
  const _Float16* wp = PWh + (long)(o0 + l15) * 384 + g * 8;

  floatx4 zero4 = {0.f, 0.f, 0.f, 0.f};
  floatx4 acc0 = zero4, acc1 = zero4, acc2 = zero4, acc3 = zero4;

  half8 bf  = *(const half8*)yp;
  half8 af0 = *(const half8*)(wp);
  half8 af1 = *(const half8*)(wp + 6144);
  half8 af2 = *(const half8*)(wp + 12288);
  half8 af3 = *(const half8*)(wp + 18432);

  #pragma unroll
  for (int cb = 0; cb < 12; cb++) {
    half8 bc = bf, a0 = af0, a1 = af1, a2 = af2, a3 = af3;
    if (cb < 11) {
      bf  = *(const half8*)(yp + (cb + 1) * 32768);
      af0 = *(const half8*)(wp + (cb + 1) * 32);
      af1 = *(const half8*)(wp + 6144 + (cb + 1) * 32);
      af2 = *(const half8*)(wp + 12288 + (cb + 1) * 32);
      af3 = *(const half8*)(wp + 18432 + (cb + 1) * 32);
    }
    acc0 = __builtin_amdgcn_mfma_f32_16x16x32_f16(a0, bc, acc0, 0, 0, 0);
    acc1 = __builtin_amdgcn_mfma_f32_16x16x32_f16(a1, bc, acc1, 0, 0, 0);
    acc2 = __builtin_amdgcn_mfma_f32_16x16x32_f16(a2, bc, acc2, 0, 0, 0);
    acc3 = __builtin_amdgcn_mfma_f32_16x16x32_f16(a3, bc, acc3, 0, 0, 0);
  }

  floatx4 acc[4] = {acc0, acc1, acc2, acc3};
  #pragma unroll
  for (int rt = 0; rt < 4; rt++) {
    int o_ = o0 + rt * 16 + g * 4;
    #pragma unroll
    for (int r = 0; r < 4; r++) {
      out[(long)(b * 384 + o_ + r) * 1024 + mcol] = acc[rt][r] + PB[o_ + r];
    }
  }
}

extern "C" void kernel_launch(void* const* d_in, const int* in_sizes, int n_in,
                              void* d_out, int out_size, void* d_ws, size_t ws_size,
                              hipStream_t stream) {
  const float* x     = (const float*)d_in[0];
  const float* qkv_w = (const float*)d_in[1];
  const float* lam   = (const float*)d_in[2];
  const float* gw    = (const float*)d_in[3];
  const float* gb    = (const float*)d_in[4];
  const float* pw    = (const float*)d_in[5];
  const float* pb    = (const float*)d_in[6];
  float* out = (float*)d_out;
  char* ws = (char*)d_ws;
  _Float16* Qs  = (_Float16*)ws;
  _Float16* Ks  = (_Float16*)(ws + 8388608);
  _Float16* Vs  = (_Float16*)(ws + 16777216);
  float* Y        = (float*)(ws + 25165824);
  float* partial  = (float*)(ws + 37748736);
  _Float16* Xt  = (_Float16*)(ws + 37752832);
  _Float16* Yt  = (_Float16*)(ws + 44044288);
  _Float16* Wh  = (_Float16*)(ws + 50335744);
  _Float16* PWh = (_Float16*)(ws + 51220480);

  hipLaunchKernelGGL(k_cvt,     dim3(216),        dim3(256), 0, stream, qkv_w, Wh, 442368);
  hipLaunchKernelGGL(k_cvt,     dim3(72),         dim3(256), 0, stream, pw, PWh, 147456);
  hipLaunchKernelGGL(k_tr,      dim3(12, 4, 8),   dim3(256), 0, stream, x, Xt);
  hipLaunchKernelGGL(k_qkv,     dim3(24, 16, 8),  dim3(256), 0, stream, Xt, Wh, Qs, Ks, Vs);
  hipLaunchKernelGGL(k_gnstats, dim3(128),        dim3(256), 0, stream, Qs, partial);
  hipLaunchKernelGGL(k_gnapply, dim3(1536),       dim3(256), 0, stream, Qs, partial, lam, gw, gb);
  hipLaunchKernelGGL(k_attn,    dim3(2048),       dim3(64),  0, stream, Qs, Ks, Vs, Y);
  hipLaunchKernelGGL(k_tr,      dim3(12, 4, 8),   dim3(256), 0, stream, Y, Yt);
  hipLaunchKernelGGL(k_proj,    dim3(6, 16, 8),   dim3(256), 0, stream, Yt, PWh, pb, out);
}

// Round 7
// 151.106 us; speedup vs baseline: 1.8762x; 1.0995x over previous
//
#include <hip/hip_runtime.h>
#include <hip/hip_bf16.h>
#include <stdint.h>

typedef _Float16 half8 __attribute__((ext_vector_type(8)));
typedef _Float16 half4 __attribute__((ext_vector_type(4)));
typedef __fp16 fp16x2 __attribute__((ext_vector_type(2)));
typedef float floatx4 __attribute__((ext_vector_type(4)));
typedef float floatx16 __attribute__((ext_vector_type(16)));

#define SCALE 0.14433756729740643f
#define LOG2E 1.4426950408889634f

// ws layout (bytes):
// Qswz f16 [64bh][32ntile][4t][64lane][8]  off 0         (8 MB) fragment-major Q
// Kswz f16 [64bh][32win][4t][64lane][8]    off 8388608   (8 MB) fragment-major K
// Vswz f16 [64bh][32win][2c][2kc][64][8]   off 16777216  (8 MB) fragment-major V
// Y    f32 [8][384][1024]                  off 25165824  scrambled pre-proj tensor
// partial f32 [128][2]                     off 37748736
// Xt   f16 [8][12][1024][32]               off 37752832
// Yt   f16 [8][12][1024][32]               off 44044288
// Wh   f16 [1152][384]                     off 50335744
// PWh  f16 [384][384]                      off 51220480
//
// Q/K logical cols (64): 0..23 q1, 24..31 zero, 32..55 q2, 56..63 zero.
// col <-> (t,hi,j): col = t*16 + hi*8 + j ; slot lane = hi*32 + l31(row).
// V logical rows (64): 0..47 v, 48 ones, 49..63 zero; element j <-> m-offset
// kc*16 + hi*4 + (j&3) + 8*(j>>2).

__device__ inline float fexp2(float x) { return __builtin_exp2f(x); }

__device__ inline uint32_t pkrtz(float a, float b) {
  fp16x2 h = __builtin_amdgcn_cvt_pkrtz(a, b);
  union { fp16x2 h; uint32_t u; } cv; cv.h = h; return cv.u;
}

// ---------------- f32 -> f16 convert (contiguous) ----------------
__global__ void k_cvt(const float* __restrict__ src, _Float16* __restrict__ dst, int n) {
  int i = (blockIdx.x * 256 + threadIdx.x) * 8;
  if (i >= n) return;
  floatx4 a = *(const floatx4*)(src + i);
  floatx4 b = *(const floatx4*)(src + i + 4);
  half8 h;
  #pragma unroll
  for (int j = 0; j < 4; j++) { h[j] = (_Float16)a[j]; h[j+4] = (_Float16)b[j]; }
  *(half8*)(dst + i) = h;
}

// ---------------- transpose-convert: [384][1024] f32 -> [12][1024][32] f16 per b ----
__launch_bounds__(256)
__global__ void k_tr(const float* __restrict__ src, _Float16* __restrict__ dst) {
  const int cblk = blockIdx.x, nseg = blockIdx.y, b = blockIdx.z;
  const float* S = src + ((long)b * 384 + cblk * 32) * 1024 + nseg * 256;
  _Float16* D = dst + (long)b * 393216 + cblk * 32768 + (long)nseg * 256 * 32;
  __shared__ _Float16 T[32][264];
  const int wv = threadIdx.x >> 6, lane = threadIdx.x & 63;
  #pragma unroll
  for (int rr = 0; rr < 8; rr++) {
    int r = wv * 8 + rr;
    floatx4 v = *(const floatx4*)(S + (long)r * 1024 + lane * 4);
    half4 h;
    #pragma unroll
    for (int j = 0; j < 4; j++) h[j] = (_Float16)v[j];
    *(half4*)&T[r][lane * 4] = h;
  }
  __syncthreads();
  const int nn = threadIdx.x >> 3, c = (threadIdx.x & 7) * 4;
  #pragma unroll
  for (int p = 0; p < 8; p++) {
    int n = p * 32 + nn;
    half4 h;
    #pragma unroll
    for (int i = 0; i < 4; i++) h[i] = T[c + i][n];
    *(half4*)(D + (long)n * 32 + c) = h;
  }
}

// ---------------- QKV GEMM: Wh(1152x384) @ Xt per batch -> swizzled Q/K/V ----------
__launch_bounds__(256)
__global__ void k_qkv(const _Float16* __restrict__ Xt, const _Float16* __restrict__ Wh,
                      _Float16* __restrict__ Qs, _Float16* __restrict__ Ks,
                      _Float16* __restrict__ Vs) {
  const int tid = threadIdx.x;
  const int lane = tid & 63;
  const int wv = tid >> 6;
  const int l15 = lane & 15;
  const int g = lane >> 4;
  const int o0 = blockIdx.x * 48;
  const int n0 = blockIdx.y * 64;
  const int b = blockIdx.z;

  const int ncol = n0 + wv * 16 + l15;
  const _Float16* xp = Xt + (long)b * 393216 + (long)ncol * 32 + g * 8;
  const _Float16* wp = Wh + (long)(o0 + l15) * 384 + g * 8;

  floatx4 zero4 = {0.f, 0.f, 0.f, 0.f};
  floatx4 acc0 = zero4, acc1 = zero4, acc2 = zero4;

  half8 bf  = *(const half8*)xp;
  half8 af0 = *(const half8*)(wp);
  half8 af1 = *(const half8*)(wp + 6144);
  half8 af2 = *(const half8*)(wp + 12288);

  #pragma unroll
  for (int cb = 0; cb < 12; cb++) {
    half8 bc = bf, a0 = af0, a1 = af1, a2 = af2;
    if (cb < 11) {
      bf  = *(const half8*)(xp + (cb + 1) * 32768);
      af0 = *(const half8*)(wp + (cb + 1) * 32);
      af1 = *(const half8*)(wp + 6144 + (cb + 1) * 32);
      af2 = *(const half8*)(wp + 12288 + (cb + 1) * 32);
    }
    acc0 = __builtin_amdgcn_mfma_f32_16x16x32_f16(a0, bc, acc0, 0, 0, 0);
    acc1 = __builtin_amdgcn_mfma_f32_16x16x32_f16(a1, bc, acc1, 0, 0, 0);
    acc2 = __builtin_amdgcn_mfma_f32_16x16x32_f16(a2, bc, acc2, 0, 0, 0);
  }

  floatx4 acc[3] = {acc0, acc1, acc2};
  __shared__ __align__(16) _Float16 T[3456];   // max(64*52, 48*72)

  if (o0 < 768) {
    // q or k rows: dump transposed T[n(64)][o48, stride 52]
    #pragma unroll
    for (int rt = 0; rt < 3; rt++)
      #pragma unroll
      for (int r = 0; r < 4; r++)
        T[(wv * 16 + l15) * 52 + rt * 16 + g * 4 + r] = (_Float16)acc[rt][r];
    __syncthreads();
    const int qk = o0 >= 384;
    const int hh = (o0 - qk * 384) / 48;
    _Float16* base = (qk ? Ks : Qs) + (long)(b * 8 + hh) * 65536;
    #pragma unroll
    for (int it = 0; it < 2; it++) {
      int slot = it * 256 + tid;          // (ntl, t, ln)
      int ntl = slot >> 8;
      int t   = (slot >> 6) & 3;
      int ln  = slot & 63;
      int hi_s = ln >> 5, l31_s = ln & 31;
      int n_ = ntl * 32 + l31_s;
      int c0 = t * 16 + hi_s * 8;
      half8 val;
      #pragma unroll
      for (int j = 0; j < 8; j++) {
        int col = c0 + j;
        int d48 = col < 24 ? col : col - 8;
        bool isq = (col < 24) || (col >= 32 && col < 56);
        val[j] = isq ? T[n_ * 52 + d48] : (_Float16)0;
      }
      *(half8*)(base + ((((n0 >> 5) + ntl) * 4 + t) * 64 + ln) * 8) = val;
    }
  } else {
    // v rows: natural dump T[o48][n(64), stride 72]
    #pragma unroll
    for (int rt = 0; rt < 3; rt++)
      #pragma unroll
      for (int r = 0; r < 4; r++)
        T[(rt * 16 + g * 4 + r) * 72 + wv * 16 + l15] = (_Float16)acc[rt][r];
    __syncthreads();
    const int hh = (o0 - 768) / 48;
    _Float16* base = Vs + (long)(b * 8 + hh) * 65536;
    #pragma unroll
    for (int it = 0; it < 2; it++) {
      int slot = it * 256 + tid;          // (lwin, ckc, ln)
      int lwin = slot >> 8;
      int ckc  = (slot >> 6) & 3;
      int kc   = ckc & 1, c = ckc >> 1;
      int ln = slot & 63;
      int hi_s = ln >> 5, l31_s = ln & 31;
      int d48 = c * 32 + l31_s;
      half8 val;
      if (d48 < 48) {
        int mb = lwin * 32 + kc * 16 + hi_s * 4;
        half4 a = *(const half4*)&T[d48 * 72 + mb];
        half4 bq = *(const half4*)&T[d48 * 72 + mb + 8];
        val[0] = a[0]; val[1] = a[1]; val[2] = a[2]; val[3] = a[3];
        val[4] = bq[0]; val[5] = bq[1]; val[6] = bq[2]; val[7] = bq[3];
      } else {
        _Float16 f = (d48 == 48) ? (_Float16)1 : (_Float16)0;
        #pragma unroll
        for (int j = 0; j < 8; j++) val[j] = f;
      }
      *(half8*)(base + ((((n0 >> 5) + lwin) * 4 + ckc) * 64 + ln) * 8) = val;
    }
  }
}

// ---------------- GroupNorm stats over swizzled q2 (deterministic partials) -------
__global__ void k_gnstats(const _Float16* __restrict__ Qs, float* __restrict__ partial) {
  int bg = blockIdx.x >> 3;
  int chunk = blockIdx.x & 7;
  int b = bg >> 1, grp = bg & 1;
  float s1 = 0.f, s2 = 0.f;
  #pragma unroll
  for (int k = 0; k < 6; k++) {
    int f = chunk * 1536 + k * 256 + threadIdx.x;
    int uid = f / 96;            // (h4, ntile32) unit within (b,grp)
    int slot = f - uid * 96;     // 0..63 -> t2 ; 64..95 -> t3 lanes 0..31
    int h = grp * 4 + (uid >> 5);
    int ntile = uid & 31;
    int t = slot < 64 ? 2 : 3;
    int ln = slot < 64 ? slot : slot - 64;
    const _Float16* p = Qs + (long)(b * 8 + h) * 65536 + ((ntile * 4 + t) * 64 + ln) * 8;
    half8 v = *(const half8*)p;
    #pragma unroll
    for (int j = 0; j < 8; j++) { float x = (float)v[j]; s1 += x; s2 += x * x; }
  }
  #pragma unroll
  for (int off = 32; off > 0; off >>= 1) {
    s1 += __shfl_down(s1, off);
    s2 += __shfl_down(s2, off);
  }
  __shared__ float red[8];
  int wv = threadIdx.x >> 6;
  if ((threadIdx.x & 63) == 0) { red[wv] = s1; red[4 + wv] = s2; }
  __syncthreads();
  if (threadIdx.x == 0) {
    float S1 = red[0] + red[1] + red[2] + red[3];
    float S2 = red[4] + red[5] + red[6] + red[7];
    partial[blockIdx.x * 2]     = S1;
    partial[blockIdx.x * 2 + 1] = S2;
  }
}

// ---------------- GN apply + fold scale*log2e, on swizzled Q ----------------
__global__ void k_gnapply(_Float16* __restrict__ Qs, const float* __restrict__ partial,
                          const float* __restrict__ lam, const float* __restrict__ gw,
                          const float* __restrict__ gb) {
  int G = blockIdx.x * 256 + threadIdx.x;   // 393216 chunks of 8 halves
  int g = G / 192;
  int r = G - g * 192;
  int bh = g >> 5, ntile = g & 31;
  int b = bh >> 3, h = bh & 7, grp = h >> 2;
  const float* pp = partial + (b * 2 + grp) * 16;
  float S1 = 0.f, S2 = 0.f;
  #pragma unroll
  for (int i = 0; i < 8; i++) { S1 += pp[2*i]; S2 += pp[2*i+1]; }
  float mean = S1 * (1.f / 98304.f);
  float rstd = rsqrtf(S2 * (1.f / 98304.f) - mean * mean + 1e-5f);
  const float s1s = SCALE * LOG2E;
  float sl = s1s * lam[h];
  int t, ln;
  if (r < 64)       { t = 0; ln = r; }
  else if (r < 96)  { t = 1; ln = r - 64; }
  else if (r < 160) { t = 2; ln = r - 96; }
  else              { t = 3; ln = r - 160; }
  int hi = ln >> 5;
  _Float16* p = Qs + (long)bh * 65536 + ((ntile * 4 + t) * 64 + ln) * 8;
  half8 v = *(half8*)p;
  if (t < 2) {
    #pragma unroll
    for (int j = 0; j < 8; j++) v[j] = (_Float16)((float)v[j] * s1s);
  } else {
    int cbase = (t == 2) ? hi * 8 : 16;
    #pragma unroll
    for (int j = 0; j < 8; j++) {
      int c = cbase + j;
      v[j] = (_Float16)((((float)v[j] - mean) * rstd * gw[h * 24 + c] + gb[h * 24 + c]) * sl);
    }
  }
  *(half8*)p = v;
}

// ---------------- fused dual-softmax attention: 8-wave cooperative blocks ----------
// Block = (bh, 4-ntile group). Wave (wv) = (ntile = grp*4 + wv>>1, branch = wv&1).
// K/V staged per 32-key window into double-buffered LDS (8KB/win, 1KB/wave async
// stage: global->reg early, ds_write late), one __syncthreads per window. Each
// wave: 2 QK MFMA + 16 exp2 + 8 pkrtz + 4 PV MFMA into 32 acc regs. Branch pair
// combines via LDS after the loop; even wave does the epilogue (identical math
// to the passing round-6 kernel).
__launch_bounds__(512, 4)
__global__ void k_attn(const _Float16* __restrict__ Qs, const _Float16* __restrict__ Ks,
                       const _Float16* __restrict__ Vs, float* __restrict__ Y) {
  const int tid = threadIdx.x;
  const int lane = tid & 63;
  const int wv = tid >> 6;          // 0..7
  const int l31 = lane & 31;
  const int hi = lane >> 5;
  const int id = blockIdx.x;
  const int bh = ((id >> 6) << 3) | (id & 7);   // all 8 ntile-groups of a head on one XCD slot
  const int ntlgrp = (id >> 3) & 7;
  const int br = wv & 1;
  const int ntile = ntlgrp * 4 + (wv >> 1);
  const int n0 = ntile * 32;

  const _Float16* Khead = Ks + (long)bh * 65536;
  const _Float16* Vhead = Vs + (long)bh * 65536;
  const _Float16* Qp = Qs + (long)bh * 65536 + (ntile * 256 + lane) * 8;

  half8 qfa = *(const half8*)(Qp + (2 * br) * 512);
  half8 qfb = *(const half8*)(Qp + (2 * br + 1) * 512);

  __shared__ __align__(16) char smem[32768];   // [2 bufs][K 4KB | V 4KB]; reused for reduction

  // this wave's 1KB staging chunk (waves 0-3: K frag wv; waves 4-7: V frag wv-4)
  const _Float16* gsrc = (wv < 4 ? Khead + wv * 512 : Vhead + (wv - 4) * 512) + lane * 8;
  const int ldsoff = (wv < 4 ? 0 : 4096) + (wv & 3) * 1024 + lane * 16;

  floatx16 z16;
  #pragma unroll
  for (int i = 0; i < 16; i++) z16[i] = 0.f;
  floatx16 accA = z16, accB = z16;

  // prologue: stage window 0 into buf0
  {
    uint4 s0 = *(const uint4*)gsrc;
    *(uint4*)(smem + ldsoff) = s0;
  }
  __syncthreads();

  #pragma unroll 2
  for (int w = 0; w < 32; w++) {
    const int cur = (w & 1) << 13;
    uint4 stg;
    if (w < 31) stg = *(const uint4*)(gsrc + (w + 1) * 2048);   // issue early

    const char* Kb = smem + cur;
    const char* Vb = smem + cur + 4096;
    half8 kfa = *(const half8*)(Kb + (2 * br) * 1024 + lane * 16);
    half8 kfb = *(const half8*)(Kb + (2 * br + 1) * 1024 + lane * 16);

    floatx16 s = __builtin_amdgcn_mfma_f32_32x32x16_f16(kfa, qfa, z16, 0, 0, 0);
    s = __builtin_amdgcn_mfma_f32_32x32x16_f16(kfb, qfb, s, 0, 0, 0);

    half8 vf0 = *(const half8*)(Vb + lane * 16);
    half8 vf1 = *(const half8*)(Vb + 1024 + lane * 16);
    half8 vf2 = *(const half8*)(Vb + 2048 + lane * 16);
    half8 vf3 = *(const half8*)(Vb + 3072 + lane * 16);

    uint32_t u[8];
    #pragma unroll
    for (int q = 0; q < 8; q++)
      u[q] = pkrtz(fexp2(s[2 * q]), fexp2(s[2 * q + 1]));

    union { uint32_t u[4]; half8 h; } pa;
    pa.u[0] = u[0]; pa.u[1] = u[1]; pa.u[2] = u[2]; pa.u[3] = u[3];
    half8 pc0 = pa.h;
    pa.u[0] = u[4]; pa.u[1] = u[5]; pa.u[2] = u[6]; pa.u[3] = u[7];
    half8 pc1 = pa.h;

    accA = __builtin_amdgcn_mfma_f32_32x32x16_f16(pc0, vf0, accA, 0, 0, 0);
    accA = __builtin_amdgcn_mfma_f32_32x32x16_f16(pc1, vf1, accA, 0, 0, 0);
    accB = __builtin_amdgcn_mfma_f32_32x32x16_f16(pc0, vf2, accB, 0, 0, 0);
    accB = __builtin_amdgcn_mfma_f32_32x32x16_f16(pc1, vf3, accB, 0, 0, 0);

    if (w < 31) *(uint4*)(smem + (cur ^ 8192) + ldsoff) = stg;  // write late
    __syncthreads();
  }

  // branch combine: odd waves dump accs, even waves combine + epilogue
  const int pairid = wv >> 1;
  float* rbuf = (float*)(smem + pairid * 8192);
  if (br == 1) {
    #pragma unroll
    for (int r = 0; r < 16; r++) {
      rbuf[r * 64 + lane] = accA[r];
      rbuf[(16 + r) * 64 + lane] = accB[r];
    }
  }
  __syncthreads();
  if (br == 0) {
    float a2a[16], a2b[16];
    #pragma unroll
    for (int r = 0; r < 16; r++) {
      a2a[r] = rbuf[r * 64 + lane];
      a2b[r] = rbuf[(16 + r) * 64 + lane];
    }
    float* Ybh = Y + (long)bh * 49152;
    const int src = (lane & 32) + 16;
    #pragma unroll
    for (int r = 0; r < 16; r++) {
      float i1 = __builtin_amdgcn_rcpf(__shfl(accB[r], src));
      float i2 = __builtin_amdgcn_rcpf(__shfl(a2b[r], src));
      int n = n0 + (r & 3) + 8 * ((r >> 2) & 3) + 4 * hi;
      float o0 = accA[r] * i1 - a2a[r] * i2;   // d = l31
      float o1 = accB[r] * i1 - a2b[r] * i2;   // d = 32 + l31 (valid < 48)
      int p0 = l31 >= 24;
      Ybh[p0 * 24576 + n * 24 + (l31 - p0 * 24)] = o0;
      if (l31 < 16) Ybh[24576 + n * 24 + 8 + l31] = o1;
    }
  }
}

// ---------------- proj GEMM: PWh(384x384) @ Yt + b ----------------
__launch_bounds__(256)
__global__ void k_proj(const _Float16* __restrict__ Yt, const _Float16* __restrict__ PWh,
                       const float* __restrict__ PB, float* __restrict__ out) {
  const int tid = threadIdx.x, lane = tid & 63, wv = tid >> 6, l15 = lane & 15, g = lane >> 4;
  const int o0 = blockIdx.x * 64, m0 = blockIdx.y * 64, b = blockIdx.z;

  const int mcol = m0 + wv * 16 + l15;
  const _Float16* yp = Yt + (long)b * 393216 + (long)mcol * 32 + g * 8;
  const _Float16* wp = PWh + (long)(o0 + l15) * 384 + g * 8;

  floatx4 zero4 = {0.f, 0.f, 0.f, 0.f};
  floatx4 acc0 = zero4, acc1 = zero4, acc2 = zero4, acc3 = zero4;

  half8 bf  = *(const half8*)yp;
  half8 af0 = *(const half8*)(wp);
  half8 af1 = *(const half8*)(wp + 6144);
  half8 af2 = *(const half8*)(wp + 12288);
  half8 af3 = *(const half8*)(wp + 18432);

  #pragma unroll
  for (int cb = 0; cb < 12; cb++) {
    half8 bc = bf, a0 = af0, a1 = af1, a2 = af2, a3 = af3;
    if (cb < 11) {
      bf  = *(const half8*)(yp + (cb + 1) * 32768);
      af0 = *(const half8*)(wp + (cb + 1) * 32);
      af1 = *(const half8*)(wp + 6144 + (cb + 1) * 32);
      af2 = *(const half8*)(wp + 12288 + (cb + 1) * 32);
      af3 = *(const half8*)(wp + 18432 + (cb + 1) * 32);
    }
    acc0 = __builtin_amdgcn_mfma_f32_16x16x32_f16(a0, bc, acc0, 0, 0, 0);
    acc1 = __builtin_amdgcn_mfma_f32_16x16x32_f16(a1, bc, acc1, 0, 0, 0);
    acc2 = __builtin_amdgcn_mfma_f32_16x16x32_f16(a2, bc, acc2, 0, 0, 0);
    acc3 = __builtin_amdgcn_mfma_f32_16x16x32_f16(a3, bc, acc3, 0, 0, 0);
  }

  floatx4 acc[4] = {acc0, acc1, acc2, acc3};
  #pragma unroll
  for (int rt = 0; rt < 4; rt++) {
    int o_ = o0 + rt * 16 + g * 4;
    #pragma unroll
    for (int r = 0; r < 4; r++) {
      out[(long)(b * 384 + o_ + r) * 1024 + mcol] = acc[rt][r] + PB[o_ + r];
    }
  }
}

extern "C" void kernel_launch(void* const* d_in, const int* in_sizes, int n_in,
                              void* d_out, int out_size, void* d_ws, size_t ws_size,
                              hipStream_t stream) {
  const float* x     = (const float*)d_in[0];
  const float* qkv_w = (const float*)d_in[1];
  const float* lam   = (const float*)d_in[2];
  const float* gw    = (const float*)d_in[3];
  const float* gb    = (const float*)d_in[4];
  const float* pw    = (const float*)d_in[5];
  const float* pb    = (const float*)d_in[6];
  float* out = (float*)d_out;
  char* ws = (char*)d_ws;
  _Float16* Qs  = (_Float16*)ws;
  _Float16* Ks  = (_Float16*)(ws + 8388608);
  _Float16* Vs  = (_Float16*)(ws + 16777216);
  float* Y        = (float*)(ws + 25165824);
  float* partial  = (float*)(ws + 37748736);
  _Float16* Xt  = (_Float16*)(ws + 37752832);
  _Float16* Yt  = (_Float16*)(ws + 44044288);
  _Float16* Wh  = (_Float16*)(ws + 50335744);
  _Float16* PWh = (_Float16*)(ws + 51220480);

  hipLaunchKernelGGL(k_cvt,     dim3(216),        dim3(256), 0, stream, qkv_w, Wh, 442368);
  hipLaunchKernelGGL(k_cvt,     dim3(72),         dim3(256), 0, stream, pw, PWh, 147456);
  hipLaunchKernelGGL(k_tr,      dim3(12, 4, 8),   dim3(256), 0, stream, x, Xt);
  hipLaunchKernelGGL(k_qkv,     dim3(24, 16, 8),  dim3(256), 0, stream, Xt, Wh, Qs, Ks, Vs);
  hipLaunchKernelGGL(k_gnstats, dim3(128),        dim3(256), 0, stream, Qs, partial);
  hipLaunchKernelGGL(k_gnapply, dim3(1536),       dim3(256), 0, stream, Qs, partial, lam, gw, gb);
  hipLaunchKernelGGL(k_attn,    dim3(512),        dim3(512), 0, stream, Qs, Ks, Vs, Y);
  hipLaunchKernelGGL(k_tr,      dim3(12, 4, 8),   dim3(256), 0, stream, Y, Yt);
  hipLaunchKernelGGL(k_proj,    dim3(6, 16, 8),   dim3(256), 0, stream, Yt, PWh, pb, out);
}

// Round 8
// 107.445 us; speedup vs baseline: 2.6386x; 1.4064x over previous
//
#include <hip/hip_runtime.h>
#include <hip/hip_bf16.h>
#include <stdint.h>

typedef _Float16 half8 __attribute__((ext_vector_type(8)));
typedef _Float16 half4 __attribute__((ext_vector_type(4)));
typedef __fp16 fp16x2 __attribute__((ext_vector_type(2)));
typedef float floatx4 __attribute__((ext_vector_type(4)));
typedef float floatx16 __attribute__((ext_vector_type(16)));

#define SCALE 0.14433756729740643f
#define LOG2E 1.4426950408889634f

// ws layout (bytes):
// Qswz f16 [64bh][32ntile][4t][64lane][8]  off 0         (8 MB) fragment-major Q
// Kswz f16 [64bh][32win][4t][64lane][8]    off 8388608   (8 MB) fragment-major K
// Vswz f16 [64bh][32win][2c][2kc][64][8]   off 16777216  (8 MB) fragment-major V
// Y    f32 [8][384][1024]                  off 25165824  scrambled pre-proj tensor
// partial f32 [128][2]                     off 37748736
// Xt   f16 [8][12][1024][32]               off 37752832
// Yt   f16 [8][12][1024][32]               off 44044288
// Wf   f16 [72g16][12cb][64lane][8]        off 50335744  fragment-major qkv_w
// PWf  f16 [24g16][12cb][64lane][8]        off 51220480  fragment-major proj_w
//
// Q/K logical cols (64): 0..23 q1, 24..31 zero, 32..55 q2, 56..63 zero.
// col <-> (t,hi,j): col = t*16 + hi*8 + j ; slot lane = hi*32 + l31(row).
// V logical rows (64): 0..47 v, 48 ones, 49..63 zero; element j <-> m-offset
// kc*16 + hi*4 + (j&3) + 8*(j>>2).
// W frag-major: chunk[(g16*12+cb)*64+lane] = w[g16*16 + (lane&15)][cb*32+(lane>>4)*8 ..+8]

__device__ inline float fexp2(float x) { return __builtin_exp2f(x); }

__device__ inline uint32_t pkrtz(float a, float b) {
  fp16x2 h = __builtin_amdgcn_cvt_pkrtz(a, b);
  union { fp16x2 h; uint32_t u; } cv; cv.h = h; return cv.u;
}

// ---------------- pack W rows into fragment-major f16 chunks ----------------
__global__ void k_pack(const float* __restrict__ src, _Float16* __restrict__ dst, int nchunks) {
  int cid = blockIdx.x * 256 + threadIdx.x;
  if (cid >= nchunks) return;
  int lane = cid & 63;
  int t = cid >> 6;
  int cb = t % 12;
  int g16 = t / 12;
  const float* s = src + (long)(g16 * 16 + (lane & 15)) * 384 + cb * 32 + (lane >> 4) * 8;
  floatx4 a = *(const floatx4*)s;
  floatx4 b = *(const floatx4*)(s + 4);
  half8 h;
  #pragma unroll
  for (int j = 0; j < 4; j++) { h[j] = (_Float16)a[j]; h[j+4] = (_Float16)b[j]; }
  *(half8*)(dst + (long)cid * 8) = h;
}

// ---------------- transpose-convert: [384][1024] f32 -> [12][1024][32] f16 per b ----
__launch_bounds__(256)
__global__ void k_tr(const float* __restrict__ src, _Float16* __restrict__ dst) {
  const int cblk = blockIdx.x, nseg = blockIdx.y, b = blockIdx.z;
  const float* S = src + ((long)b * 384 + cblk * 32) * 1024 + nseg * 256;
  _Float16* D = dst + (long)b * 393216 + cblk * 32768 + (long)nseg * 256 * 32;
  __shared__ _Float16 T[32][264];
  const int wv = threadIdx.x >> 6, lane = threadIdx.x & 63;
  #pragma unroll
  for (int rr = 0; rr < 8; rr++) {
    int r = wv * 8 + rr;
    floatx4 v = *(const floatx4*)(S + (long)r * 1024 + lane * 4);
    half4 h;
    #pragma unroll
    for (int j = 0; j < 4; j++) h[j] = (_Float16)v[j];
    *(half4*)&T[r][lane * 4] = h;
  }
  __syncthreads();
  const int nn = threadIdx.x >> 3, c = (threadIdx.x & 7) * 4;
  #pragma unroll
  for (int p = 0; p < 8; p++) {
    int n = p * 32 + nn;
    half4 h;
    #pragma unroll
    for (int i = 0; i < 4; i++) h[i] = T[c + i][n];
    *(half4*)(D + (long)n * 32 + c) = h;
  }
}

// ---------------- QKV GEMM: Wf @ Xt per batch -> swizzled Q/K/V ----------
__launch_bounds__(256, 4)
__global__ void k_qkv(const _Float16* __restrict__ Xt, const _Float16* __restrict__ Wf,
                      _Float16* __restrict__ Qs, _Float16* __restrict__ Ks,
                      _Float16* __restrict__ Vs) {
  const int tid = threadIdx.x;
  const int lane = tid & 63;
  const int wv = tid >> 6;
  const int l15 = lane & 15;
  const int g = lane >> 4;
  const int o0 = blockIdx.x * 48;
  const int n0 = blockIdx.y * 64;
  const int b = blockIdx.z;

  const int ncol = n0 + wv * 16 + l15;
  const _Float16* xp = Xt + (long)b * 393216 + (long)ncol * 32 + g * 8;
  const _Float16* wfb = Wf + (long)(blockIdx.x * 36) * 512 + lane * 8;   // (rt*12+cb)*512 strides

  // prefetch ALL 12 B-frags (independent, in flight together)
  half8 xb[12];
  #pragma unroll
  for (int cb = 0; cb < 12; cb++) xb[cb] = *(const half8*)(xp + cb * 32768);

  floatx4 zero4 = {0.f, 0.f, 0.f, 0.f};
  floatx4 acc0 = zero4, acc1 = zero4, acc2 = zero4;

  // depth-2 A pipeline
  half8 A0 = *(const half8*)(wfb);
  half8 A1 = *(const half8*)(wfb + 12 * 512);
  half8 A2 = *(const half8*)(wfb + 24 * 512);
  #pragma unroll
  for (int cb = 0; cb < 12; cb++) {
    half8 c0 = A0, c1 = A1, c2 = A2;
    if (cb < 11) {
      A0 = *(const half8*)(wfb + (cb + 1) * 512);
      A1 = *(const half8*)(wfb + (12 + cb + 1) * 512);
      A2 = *(const half8*)(wfb + (24 + cb + 1) * 512);
    }
    acc0 = __builtin_amdgcn_mfma_f32_16x16x32_f16(c0, xb[cb], acc0, 0, 0, 0);
    acc1 = __builtin_amdgcn_mfma_f32_16x16x32_f16(c1, xb[cb], acc1, 0, 0, 0);
    acc2 = __builtin_amdgcn_mfma_f32_16x16x32_f16(c2, xb[cb], acc2, 0, 0, 0);
  }

  floatx4 acc[3] = {acc0, acc1, acc2};
  __shared__ __align__(16) _Float16 T[3456];   // max(64*52, 48*72)

  if (o0 < 768) {
    // q or k rows: dump transposed T[n(64)][o48, stride 52]
    #pragma unroll
    for (int rt = 0; rt < 3; rt++)
      #pragma unroll
      for (int r = 0; r < 4; r++)
        T[(wv * 16 + l15) * 52 + rt * 16 + g * 4 + r] = (_Float16)acc[rt][r];
    __syncthreads();
    const int qk = o0 >= 384;
    const int hh = (o0 - qk * 384) / 48;
    _Float16* base = (qk ? Ks : Qs) + (long)(b * 8 + hh) * 65536;
    #pragma unroll
    for (int it = 0; it < 2; it++) {
      int slot = it * 256 + tid;          // (ntl, t, ln)
      int ntl = slot >> 8;
      int t   = (slot >> 6) & 3;
      int ln  = slot & 63;
      int hi_s = ln >> 5, l31_s = ln & 31;
      int n_ = ntl * 32 + l31_s;
      int c0 = t * 16 + hi_s * 8;
      half8 val;
      #pragma unroll
      for (int j = 0; j < 8; j++) {
        int col = c0 + j;
        int d48 = col < 24 ? col : col - 8;
        bool isq = (col < 24) || (col >= 32 && col < 56);
        val[j] = isq ? T[n_ * 52 + d48] : (_Float16)0;
      }
      *(half8*)(base + ((((n0 >> 5) + ntl) * 4 + t) * 64 + ln) * 8) = val;
    }
  } else {
    // v rows: natural dump T[o48][n(64), stride 72]
    #pragma unroll
    for (int rt = 0; rt < 3; rt++)
      #pragma unroll
      for (int r = 0; r < 4; r++)
        T[(rt * 16 + g * 4 + r) * 72 + wv * 16 + l15] = (_Float16)acc[rt][r];
    __syncthreads();
    const int hh = (o0 - 768) / 48;
    _Float16* base = Vs + (long)(b * 8 + hh) * 65536;
    #pragma unroll
    for (int it = 0; it < 2; it++) {
      int slot = it * 256 + tid;          // (lwin, ckc, ln)
      int lwin = slot >> 8;
      int ckc  = (slot >> 6) & 3;
      int kc   = ckc & 1, c = ckc >> 1;
      int ln = slot & 63;
      int hi_s = ln >> 5, l31_s = ln & 31;
      int d48 = c * 32 + l31_s;
      half8 val;
      if (d48 < 48) {
        int mb = lwin * 32 + kc * 16 + hi_s * 4;
        half4 a = *(const half4*)&T[d48 * 72 + mb];
        half4 bq = *(const half4*)&T[d48 * 72 + mb + 8];
        val[0] = a[0]; val[1] = a[1]; val[2] = a[2]; val[3] = a[3];
        val[4] = bq[0]; val[5] = bq[1]; val[6] = bq[2]; val[7] = bq[3];
      } else {
        _Float16 f = (d48 == 48) ? (_Float16)1 : (_Float16)0;
        #pragma unroll
        for (int j = 0; j < 8; j++) val[j] = f;
      }
      *(half8*)(base + ((((n0 >> 5) + lwin) * 4 + ckc) * 64 + ln) * 8) = val;
    }
  }
}

// ---------------- GroupNorm stats over swizzled q2 (deterministic partials) -------
__global__ void k_gnstats(const _Float16* __restrict__ Qs, float* __restrict__ partial) {
  int bg = blockIdx.x >> 3;
  int chunk = blockIdx.x & 7;
  int b = bg >> 1, grp = bg & 1;
  float s1 = 0.f, s2 = 0.f;
  #pragma unroll
  for (int k = 0; k < 6; k++) {
    int f = chunk * 1536 + k * 256 + threadIdx.x;
    int uid = f / 96;            // (h4, ntile32) unit within (b,grp)
    int slot = f - uid * 96;     // 0..63 -> t2 ; 64..95 -> t3 lanes 0..31
    int h = grp * 4 + (uid >> 5);
    int ntile = uid & 31;
    int t = slot < 64 ? 2 : 3;
    int ln = slot < 64 ? slot : slot - 64;
    const _Float16* p = Qs + (long)(b * 8 + h) * 65536 + ((ntile * 4 + t) * 64 + ln) * 8;
    half8 v = *(const half8*)p;
    #pragma unroll
    for (int j = 0; j < 8; j++) { float x = (float)v[j]; s1 += x; s2 += x * x; }
  }
  #pragma unroll
  for (int off = 32; off > 0; off >>= 1) {
    s1 += __shfl_down(s1, off);
    s2 += __shfl_down(s2, off);
  }
  __shared__ float red[8];
  int wv = threadIdx.x >> 6;
  if ((threadIdx.x & 63) == 0) { red[wv] = s1; red[4 + wv] = s2; }
  __syncthreads();
  if (threadIdx.x == 0) {
    float S1 = red[0] + red[1] + red[2] + red[3];
    float S2 = red[4] + red[5] + red[6] + red[7];
    partial[blockIdx.x * 2]     = S1;
    partial[blockIdx.x * 2 + 1] = S2;
  }
}

// ---------------- GN apply + fold scale*log2e, on swizzled Q ----------------
__global__ void k_gnapply(_Float16* __restrict__ Qs, const float* __restrict__ partial,
                          const float* __restrict__ lam, const float* __restrict__ gw,
                          const float* __restrict__ gb) {
  int G = blockIdx.x * 256 + threadIdx.x;   // 393216 chunks of 8 halves
  int g = G / 192;
  int r = G - g * 192;
  int bh = g >> 5, ntile = g & 31;
  int b = bh >> 3, h = bh & 7, grp = h >> 2;
  const float* pp = partial + (b * 2 + grp) * 16;
  float S1 = 0.f, S2 = 0.f;
  #pragma unroll
  for (int i = 0; i < 8; i++) { S1 += pp[2*i]; S2 += pp[2*i+1]; }
  float mean = S1 * (1.f / 98304.f);
  float rstd = rsqrtf(S2 * (1.f / 98304.f) - mean * mean + 1e-5f);
  const float s1s = SCALE * LOG2E;
  float sl = s1s * lam[h];
  int t, ln;
  if (r < 64)       { t = 0; ln = r; }
  else if (r < 96)  { t = 1; ln = r - 64; }
  else if (r < 160) { t = 2; ln = r - 96; }
  else              { t = 3; ln = r - 160; }
  int hi = ln >> 5;
  _Float16* p = Qs + (long)bh * 65536 + ((ntile * 4 + t) * 64 + ln) * 8;
  half8 v = *(half8*)p;
  if (t < 2) {
    #pragma unroll
    for (int j = 0; j < 8; j++) v[j] = (_Float16)((float)v[j] * s1s);
  } else {
    int cbase = (t == 2) ? hi * 8 : 16;
    #pragma unroll
    for (int j = 0; j < 8; j++) {
      int c = cbase + j;
      v[j] = (_Float16)((((float)v[j] - mean) * rstd * gw[h * 24 + c] + gb[h * 24 + c]) * sl);
    }
  }
  *(half8*)p = v;
}

// ---------------- fused dual-softmax attention: 8-wave cooperative blocks ----------
__launch_bounds__(512, 4)
__global__ void k_attn(const _Float16* __restrict__ Qs, const _Float16* __restrict__ Ks,
                       const _Float16* __restrict__ Vs, float* __restrict__ Y) {
  const int tid = threadIdx.x;
  const int lane = tid & 63;
  const int wv = tid >> 6;          // 0..7
  const int l31 = lane & 31;
  const int hi = lane >> 5;
  const int id = blockIdx.x;
  const int bh = ((id >> 6) << 3) | (id & 7);   // all 8 ntile-groups of a head on one XCD slot
  const int ntlgrp = (id >> 3) & 7;
  const int br = wv & 1;
  const int ntile = ntlgrp * 4 + (wv >> 1);
  const int n0 = ntile * 32;

  const _Float16* Khead = Ks + (long)bh * 65536;
  const _Float16* Vhead = Vs + (long)bh * 65536;
  const _Float16* Qp = Qs + (long)bh * 65536 + (ntile * 256 + lane) * 8;

  half8 qfa = *(const half8*)(Qp + (2 * br) * 512);
  half8 qfb = *(const half8*)(Qp + (2 * br + 1) * 512);

  __shared__ __align__(16) char smem[32768];   // [2 bufs][K 4KB | V 4KB]; reused for reduction

  const _Float16* gsrc = (wv < 4 ? Khead + wv * 512 : Vhead + (wv - 4) * 512) + lane * 8;
  const int ldsoff = (wv < 4 ? 0 : 4096) + (wv & 3) * 1024 + lane * 16;

  floatx16 z16;
  #pragma unroll
  for (int i = 0; i < 16; i++) z16[i] = 0.f;
  floatx16 accA = z16, accB = z16;

  {
    uint4 s0 = *(const uint4*)gsrc;
    *(uint4*)(smem + ldsoff) = s0;
  }
  __syncthreads();

  #pragma unroll 2
  for (int w = 0; w < 32; w++) {
    const int cur = (w & 1) << 13;
    uint4 stg;
    if (w < 31) stg = *(const uint4*)(gsrc + (w + 1) * 2048);   // issue early

    const char* Kb = smem + cur;
    const char* Vb = smem + cur + 4096;
    half8 kfa = *(const half8*)(Kb + (2 * br) * 1024 + lane * 16);
    half8 kfb = *(const half8*)(Kb + (2 * br + 1) * 1024 + lane * 16);

    floatx16 s = __builtin_amdgcn_mfma_f32_32x32x16_f16(kfa, qfa, z16, 0, 0, 0);
    s = __builtin_amdgcn_mfma_f32_32x32x16_f16(kfb, qfb, s, 0, 0, 0);

    half8 vf0 = *(const half8*)(Vb + lane * 16);
    half8 vf1 = *(const half8*)(Vb + 1024 + lane * 16);
    half8 vf2 = *(const half8*)(Vb + 2048 + lane * 16);
    half8 vf3 = *(const half8*)(Vb + 3072 + lane * 16);

    uint32_t u[8];
    #pragma unroll
    for (int q = 0; q < 8; q++)
      u[q] = pkrtz(fexp2(s[2 * q]), fexp2(s[2 * q + 1]));

    union { uint32_t u[4]; half8 h; } pa;
    pa.u[0] = u[0]; pa.u[1] = u[1]; pa.u[2] = u[2]; pa.u[3] = u[3];
    half8 pc0 = pa.h;
    pa.u[0] = u[4]; pa.u[1] = u[5]; pa.u[2] = u[6]; pa.u[3] = u[7];
    half8 pc1 = pa.h;

    accA = __builtin_amdgcn_mfma_f32_32x32x16_f16(pc0, vf0, accA, 0, 0, 0);
    accA = __builtin_amdgcn_mfma_f32_32x32x16_f16(pc1, vf1, accA, 0, 0, 0);
    accB = __builtin_amdgcn_mfma_f32_32x32x16_f16(pc0, vf2, accB, 0, 0, 0);
    accB = __builtin_amdgcn_mfma_f32_32x32x16_f16(pc1, vf3, accB, 0, 0, 0);

    if (w < 31) *(uint4*)(smem + (cur ^ 8192) + ldsoff) = stg;  // write late
    __syncthreads();
  }

  const int pairid = wv >> 1;
  float* rbuf = (float*)(smem + pairid * 8192);
  if (br == 1) {
    #pragma unroll
    for (int r = 0; r < 16; r++) {
      rbuf[r * 64 + lane] = accA[r];
      rbuf[(16 + r) * 64 + lane] = accB[r];
    }
  }
  __syncthreads();
  if (br == 0) {
    float a2a[16], a2b[16];
    #pragma unroll
    for (int r = 0; r < 16; r++) {
      a2a[r] = rbuf[r * 64 + lane];
      a2b[r] = rbuf[(16 + r) * 64 + lane];
    }
    float* Ybh = Y + (long)bh * 49152;
    const int src = (lane & 32) + 16;
    #pragma unroll
    for (int r = 0; r < 16; r++) {
      float i1 = __builtin_amdgcn_rcpf(__shfl(accB[r], src));
      float i2 = __builtin_amdgcn_rcpf(__shfl(a2b[r], src));
      int n = n0 + (r & 3) + 8 * ((r >> 2) & 3) + 4 * hi;
      float o0 = accA[r] * i1 - a2a[r] * i2;   // d = l31
      float o1 = accB[r] * i1 - a2b[r] * i2;   // d = 32 + l31 (valid < 48)
      int p0 = l31 >= 24;
      Ybh[p0 * 24576 + n * 24 + (l31 - p0 * 24)] = o0;
      if (l31 < 16) Ybh[24576 + n * 24 + 8 + l31] = o1;
    }
  }
}

// ---------------- proj GEMM: PWf @ Yt + b ----------------
__launch_bounds__(256, 4)
__global__ void k_proj(const _Float16* __restrict__ Yt, const _Float16* __restrict__ PWf,
                       const float* __restrict__ PB, float* __restrict__ out) {
  const int tid = threadIdx.x, lane = tid & 63, wv = tid >> 6, l15 = lane & 15, g = lane >> 4;
  const int o0 = blockIdx.x * 64, m0 = blockIdx.y * 64, b = blockIdx.z;

  const int mcol = m0 + wv * 16 + l15;
  const _Float16* yp = Yt + (long)b * 393216 + (long)mcol * 32 + g * 8;
  const _Float16* wfb = PWf + (long)(blockIdx.x * 48) * 512 + lane * 8;

  half8 yb[12];
  #pragma unroll
  for (int cb = 0; cb < 12; cb++) yb[cb] = *(const half8*)(yp + cb * 32768);

  floatx4 zero4 = {0.f, 0.f, 0.f, 0.f};
  floatx4 acc0 = zero4, acc1 = zero4, acc2 = zero4, acc3 = zero4;

  half8 A0 = *(const half8*)(wfb);
  half8 A1 = *(const half8*)(wfb + 12 * 512);
  half8 A2 = *(const half8*)(wfb + 24 * 512);
  half8 A3 = *(const half8*)(wfb + 36 * 512);
  #pragma unroll
  for (int cb = 0; cb < 12; cb++) {
    half8 c0 = A0, c1 = A1, c2 = A2, c3 = A3;
    if (cb < 11) {
      A0 = *(const half8*)(wfb + (cb + 1) * 512);
      A1 = *(const half8*)(wfb + (12 + cb + 1) * 512);
      A2 = *(const half8*)(wfb + (24 + cb + 1) * 512);
      A3 = *(const half8*)(wfb + (36 + cb + 1) * 512);
    }
    acc0 = __builtin_amdgcn_mfma_f32_16x16x32_f16(c0, yb[cb], acc0, 0, 0, 0);
    acc1 = __builtin_amdgcn_mfma_f32_16x16x32_f16(c1, yb[cb], acc1, 0, 0, 0);
    acc2 = __builtin_amdgcn_mfma_f32_16x16x32_f16(c2, yb[cb], acc2, 0, 0, 0);
    acc3 = __builtin_amdgcn_mfma_f32_16x16x32_f16(c3, yb[cb], acc3, 0, 0, 0);
  }

  floatx4 acc[4] = {acc0, acc1, acc2, acc3};
  #pragma unroll
  for (int rt = 0; rt < 4; rt++) {
    int o_ = o0 + rt * 16 + g * 4;
    #pragma unroll
    for (int r = 0; r < 4; r++) {
      out[(long)(b * 384 + o_ + r) * 1024 + mcol] = acc[rt][r] + PB[o_ + r];
    }
  }
}

extern "C" void kernel_launch(void* const* d_in, const int* in_sizes, int n_in,
                              void* d_out, int out_size, void* d_ws, size_t ws_size,
                              hipStream_t stream) {
  const float* x     = (const float*)d_in[0];
  const float* qkv_w = (const float*)d_in[1];
  const float* lam   = (const float*)d_in[2];
  const float* gw    = (const float*)d_in[3];
  const float* gb    = (const float*)d_in[4];
  const float* pw    = (const float*)d_in[5];
  const float* pb    = (const float*)d_in[6];
  float* out = (float*)d_out;
  char* ws = (char*)d_ws;
  _Float16* Qs  = (_Float16*)ws;
  _Float16* Ks  = (_Float16*)(ws + 8388608);
  _Float16* Vs  = (_Float16*)(ws + 16777216);
  float* Y        = (float*)(ws + 25165824);
  float* partial  = (float*)(ws + 37748736);
  _Float16* Xt  = (_Float16*)(ws + 37752832);
  _Float16* Yt  = (_Float16*)(ws + 44044288);
  _Float16* Wf  = (_Float16*)(ws + 50335744);
  _Float16* PWf = (_Float16*)(ws + 51220480);

  hipLaunchKernelGGL(k_pack,    dim3(216),        dim3(256), 0, stream, qkv_w, Wf, 55296);
  hipLaunchKernelGGL(k_pack,    dim3(72),         dim3(256), 0, stream, pw, PWf, 18432);
  hipLaunchKernelGGL(k_tr,      dim3(12, 4, 8),   dim3(256), 0, stream, x, Xt);
  hipLaunchKernelGGL(k_qkv,     dim3(24, 16, 8),  dim3(256), 0, stream, Xt, Wf, Qs, Ks, Vs);
  hipLaunchKernelGGL(k_gnstats, dim3(128),        dim3(256), 0, stream, Qs, partial);
  hipLaunchKernelGGL(k_gnapply, dim3(1536),       dim3(256), 0, stream, Qs, partial, lam, gw, gb);
  hipLaunchKernelGGL(k_attn,    dim3(512),        dim3(512), 0, stream, Qs, Ks, Vs, Y);
  hipLaunchKernelGGL(k_tr,      dim3(12, 4, 8),   dim3(256), 0, stream, Y, Yt);
  hipLaunchKernelGGL(k_proj,    dim3(6, 16, 8),   dim3(256), 0, stream, Yt, PWf, pb, out);
}

// Round 10
// 102.316 us; speedup vs baseline: 2.7708x; 1.0501x over previous
//
#include <hip/hip_runtime.h>
#include <hip/hip_bf16.h>
#include <stdint.h>

typedef _Float16 half8 __attribute__((ext_vector_type(8)));
typedef _Float16 half4 __attribute__((ext_vector_type(4)));
typedef __fp16 fp16x2 __attribute__((ext_vector_type(2)));
typedef float floatx4 __attribute__((ext_vector_type(4)));
typedef float floatx16 __attribute__((ext_vector_type(16)));

#define SCALE 0.14433756729740643f
#define LOG2E 1.4426950408889634f

// ws layout (bytes):
// Qswz f16 [64bh][32ntile][4t][64lane][8]  off 0         fragment-major Q (raw; GN folded in attn)
// Kswz f16 [64bh][32win][4t][64lane][8]    off 8388608   fragment-major K
// Vswz f16 [64bh][32win][2c][2kc][64][8]   off 16777216  fragment-major V
// Y    f32 [8][384][1024]                  off 25165824  scrambled pre-proj tensor (flat order)
// partial f32 [128][2]                     off 37748736
// Xt   f16 [8][12][1024][32]               off 37752832
// Yt   f16 [8][12][1024][32]               off 44044288
// Wf   f16 [72g16][12cb][64lane][8]        off 50335744  fragment-major qkv_w
// PWf  f16 [24g16][12cb][64lane][8]        off 51220480  fragment-major proj_w
//
// Q/K logical cols (64): 0..23 q1, 24..31 zero, 32..55 q2, 56..63 zero.
// col <-> (t,hi,j): col = t*16 + hi*8 + j ; slot lane = hi*32 + l31(row).
// V logical rows (64): 0..47 v, 48 ones, 49..63 zero; element j <-> m-offset
// kc*16 + hi*4 + (j&3) + 8*(j>>2).

__device__ inline float fexp2(float x) { return __builtin_exp2f(x); }

__device__ inline uint32_t pkrtz(float a, float b) {
  fp16x2 h = __builtin_amdgcn_cvt_pkrtz(a, b);
  union { fp16x2 h; uint32_t u; } cv; cv.h = h; return cv.u;
}

// ---------------- pack W rows into fragment-major f16 chunks ----------------
__global__ void k_pack(const float* __restrict__ src, _Float16* __restrict__ dst, int nchunks) {
  int cid = blockIdx.x * 256 + threadIdx.x;
  if (cid >= nchunks) return;
  int lane = cid & 63;
  int t = cid >> 6;
  int cb = t % 12;
  int g16 = t / 12;
  const float* s = src + (long)(g16 * 16 + (lane & 15)) * 384 + cb * 32 + (lane >> 4) * 8;
  floatx4 a = *(const floatx4*)s;
  floatx4 b = *(const floatx4*)(s + 4);
  half8 h;
  #pragma unroll
  for (int j = 0; j < 4; j++) { h[j] = (_Float16)a[j]; h[j+4] = (_Float16)b[j]; }
  *(half8*)(dst + (long)cid * 8) = h;
}

// ---------------- transpose-convert: [384][1024] f32 -> [12][1024][32] f16 per b ----
__launch_bounds__(256)
__global__ void k_tr(const float* __restrict__ src, _Float16* __restrict__ dst) {
  const int cblk = blockIdx.x, nseg = blockIdx.y, b = blockIdx.z;
  const float* S = src + ((long)b * 384 + cblk * 32) * 1024 + nseg * 256;
  _Float16* D = dst + (long)b * 393216 + cblk * 32768 + (long)nseg * 256 * 32;
  __shared__ _Float16 T[32][264];
  const int wv = threadIdx.x >> 6, lane = threadIdx.x & 63;
  #pragma unroll
  for (int rr = 0; rr < 8; rr++) {
    int r = wv * 8 + rr;
    floatx4 v = *(const floatx4*)(S + (long)r * 1024 + lane * 4);
    half4 h;
    #pragma unroll
    for (int j = 0; j < 4; j++) h[j] = (_Float16)v[j];
    *(half4*)&T[r][lane * 4] = h;
  }
  __syncthreads();
  const int nn = threadIdx.x >> 3, c = (threadIdx.x & 7) * 4;
  #pragma unroll
  for (int p = 0; p < 8; p++) {
    int n = p * 32 + nn;
    half4 h;
    #pragma unroll
    for (int i = 0; i < 4; i++) h[i] = T[c + i][n];
    *(half4*)(D + (long)n * 32 + c) = h;
  }
}

// ---------------- QKV GEMM: Wf @ Xt per batch -> swizzled Q/K/V ----------
__launch_bounds__(256, 4)
__global__ void k_qkv(const _Float16* __restrict__ Xt, const _Float16* __restrict__ Wf,
                      _Float16* __restrict__ Qs, _Float16* __restrict__ Ks,
                      _Float16* __restrict__ Vs) {
  const int tid = threadIdx.x;
  const int lane = tid & 63;
  const int wv = tid >> 6;
  const int l15 = lane & 15;
  const int g = lane >> 4;
  const int o0 = blockIdx.x * 48;
  const int n0 = blockIdx.y * 64;
  const int b = blockIdx.z;

  const int ncol = n0 + wv * 16 + l15;
  const _Float16* xp = Xt + (long)b * 393216 + (long)ncol * 32 + g * 8;
  const _Float16* wfb = Wf + (long)(blockIdx.x * 36) * 512 + lane * 8;

  half8 xb[12];
  #pragma unroll
  for (int cb = 0; cb < 12; cb++) xb[cb] = *(const half8*)(xp + cb * 32768);

  floatx4 zero4 = {0.f, 0.f, 0.f, 0.f};
  floatx4 acc0 = zero4, acc1 = zero4, acc2 = zero4;

  half8 A0 = *(const half8*)(wfb);
  half8 A1 = *(const half8*)(wfb + 12 * 512);
  half8 A2 = *(const half8*)(wfb + 24 * 512);
  #pragma unroll
  for (int cb = 0; cb < 12; cb++) {
    half8 c0 = A0, c1 = A1, c2 = A2;
    if (cb < 11) {
      A0 = *(const half8*)(wfb + (cb + 1) * 512);
      A1 = *(const half8*)(wfb + (12 + cb + 1) * 512);
      A2 = *(const half8*)(wfb + (24 + cb + 1) * 512);
    }
    acc0 = __builtin_amdgcn_mfma_f32_16x16x32_f16(c0, xb[cb], acc0, 0, 0, 0);
    acc1 = __builtin_amdgcn_mfma_f32_16x16x32_f16(c1, xb[cb], acc1, 0, 0, 0);
    acc2 = __builtin_amdgcn_mfma_f32_16x16x32_f16(c2, xb[cb], acc2, 0, 0, 0);
  }

  floatx4 acc[3] = {acc0, acc1, acc2};
  __shared__ __align__(16) _Float16 T[3456];   // max(64*52, 48*72)

  if (o0 < 768) {
    #pragma unroll
    for (int rt = 0; rt < 3; rt++)
      #pragma unroll
      for (int r = 0; r < 4; r++)
        T[(wv * 16 + l15) * 52 + rt * 16 + g * 4 + r] = (_Float16)acc[rt][r];
    __syncthreads();
    const int qk = o0 >= 384;
    const int hh = (o0 - qk * 384) / 48;
    _Float16* base = (qk ? Ks : Qs) + (long)(b * 8 + hh) * 65536;
    #pragma unroll
    for (int it = 0; it < 2; it++) {
      int slot = it * 256 + tid;
      int ntl = slot >> 8;
      int t   = (slot >> 6) & 3;
      int ln  = slot & 63;
      int hi_s = ln >> 5, l31_s = ln & 31;
      int n_ = ntl * 32 + l31_s;
      int c0 = t * 16 + hi_s * 8;
      half8 val;
      #pragma unroll
      for (int j = 0; j < 8; j++) {
        int col = c0 + j;
        int d48 = col < 24 ? col : col - 8;
        bool isq = (col < 24) || (col >= 32 && col < 56);
        val[j] = isq ? T[n_ * 52 + d48] : (_Float16)0;
      }
      *(half8*)(base + ((((n0 >> 5) + ntl) * 4 + t) * 64 + ln) * 8) = val;
    }
  } else {
    #pragma unroll
    for (int rt = 0; rt < 3; rt++)
      #pragma unroll
      for (int r = 0; r < 4; r++)
        T[(rt * 16 + g * 4 + r) * 72 + wv * 16 + l15] = (_Float16)acc[rt][r];
    __syncthreads();
    const int hh = (o0 - 768) / 48;
    _Float16* base = Vs + (long)(b * 8 + hh) * 65536;
    #pragma unroll
    for (int it = 0; it < 2; it++) {
      int slot = it * 256 + tid;
      int lwin = slot >> 8;
      int ckc  = (slot >> 6) & 3;
      int kc   = ckc & 1, c = ckc >> 1;
      int ln = slot & 63;
      int hi_s = ln >> 5, l31_s = ln & 31;
      int d48 = c * 32 + l31_s;
      half8 val;
      if (d48 < 48) {
        int mb = lwin * 32 + kc * 16 + hi_s * 4;
        half4 a = *(const half4*)&T[d48 * 72 + mb];
        half4 bq = *(const half4*)&T[d48 * 72 + mb + 8];
        val[0] = a[0]; val[1] = a[1]; val[2] = a[2]; val[3] = a[3];
        val[4] = bq[0]; val[5] = bq[1]; val[6] = bq[2]; val[7] = bq[3];
      } else {
        _Float16 f = (d48 == 48) ? (_Float16)1 : (_Float16)0;
        #pragma unroll
        for (int j = 0; j < 8; j++) val[j] = f;
      }
      *(half8*)(base + ((((n0 >> 5) + lwin) * 4 + ckc) * 64 + ln) * 8) = val;
    }
  }
}

// ---------------- GroupNorm stats over swizzled q2 (deterministic partials) -------
__global__ void k_gnstats(const _Float16* __restrict__ Qs, float* __restrict__ partial) {
  int bg = blockIdx.x >> 3;
  int chunk = blockIdx.x & 7;
  int b = bg >> 1, grp = bg & 1;
  float s1 = 0.f, s2 = 0.f;
  #pragma unroll
  for (int k = 0; k < 6; k++) {
    int f = chunk * 1536 + k * 256 + threadIdx.x;
    int uid = f / 96;
    int slot = f - uid * 96;
    int h = grp * 4 + (uid >> 5);
    int ntile = uid & 31;
    int t = slot < 64 ? 2 : 3;
    int ln = slot < 64 ? slot : slot - 64;
    const _Float16* p = Qs + (long)(b * 8 + h) * 65536 + ((ntile * 4 + t) * 64 + ln) * 8;
    half8 v = *(const half8*)p;
    #pragma unroll
    for (int j = 0; j < 8; j++) { float x = (float)v[j]; s1 += x; s2 += x * x; }
  }
  #pragma unroll
  for (int off = 32; off > 0; off >>= 1) {
    s1 += __shfl_down(s1, off);
    s2 += __shfl_down(s2, off);
  }
  __shared__ float red[8];
  int wv = threadIdx.x >> 6;
  if ((threadIdx.x & 63) == 0) { red[wv] = s1; red[4 + wv] = s2; }
  __syncthreads();
  if (threadIdx.x == 0) {
    float S1 = red[0] + red[1] + red[2] + red[3];
    float S2 = red[4] + red[5] + red[6] + red[7];
    partial[blockIdx.x * 2]     = S1;
    partial[blockIdx.x * 2 + 1] = S2;
  }
}

// ---------------- fused dual-softmax attention: 8-wave coop, 64-key iterations ----
// Wave = (ntile, branch). GN-apply + scale*log2e folded into the Q-load (bit-
// identical to the old k_gnapply). K/V double-buffered in LDS (2x16KB), one
// barrier per 64-key pair. Epilogue: flat f32 Y write (verified semantics,
// rounds 4-8); Y -> Yt handled by k_tr.
__launch_bounds__(512, 4)
__global__ void k_attn(const _Float16* __restrict__ Qs, const _Float16* __restrict__ Ks,
                       const _Float16* __restrict__ Vs, const float* __restrict__ partial,
                       const float* __restrict__ lam, const float* __restrict__ gw,
                       const float* __restrict__ gb, float* __restrict__ Y) {
  const int tid = threadIdx.x;
  const int lane = tid & 63;
  const int wv = tid >> 6;          // 0..7
  const int l31 = lane & 31;
  const int hi = lane >> 5;
  const int id = blockIdx.x;
  const int bh = ((id >> 6) << 3) | (id & 7);
  const int ntlgrp = (id >> 3) & 7;
  const int br = wv & 1;
  const int ntile = ntlgrp * 4 + (wv >> 1);
  const int n0 = ntile * 32;
  const int b = bh >> 3, h = bh & 7;

  // Q load + folded GN / scale (bit-identical to old k_gnapply transform)
  const _Float16* Qp = Qs + (long)bh * 65536 + (ntile * 256 + lane) * 8;
  half8 qra = *(const half8*)(Qp + (2 * br) * 512);
  half8 qrb = *(const half8*)(Qp + (2 * br + 1) * 512);
  half8 qfa, qfb;
  if (br == 0) {
    const float s1s = SCALE * LOG2E;
    #pragma unroll
    for (int j = 0; j < 8; j++) {
      qfa[j] = (_Float16)((float)qra[j] * s1s);
      qfb[j] = (_Float16)((float)qrb[j] * s1s);
    }
  } else {
    const int grp = h >> 2;
    const float* pp = partial + (b * 2 + grp) * 16;
    float S1 = 0.f, S2 = 0.f;
    #pragma unroll
    for (int i = 0; i < 8; i++) { S1 += pp[2*i]; S2 += pp[2*i+1]; }
    float mean = S1 * (1.f / 98304.f);
    float rstd = rsqrtf(S2 * (1.f / 98304.f) - mean * mean + 1e-5f);
    float sl = SCALE * LOG2E * lam[h];
    const float* gwp = gw + h * 24;
    const float* gbp = gb + h * 24;
    #pragma unroll
    for (int j = 0; j < 8; j++) {
      // t=2: c = hi*8+j (real); t=3: c = 16+j (real for hi=0; hi=1 pads become
      // garbage but annihilate against K pads == 0)
      qfa[j] = (_Float16)((((float)qra[j] - mean) * rstd * gwp[hi * 8 + j] + gbp[hi * 8 + j]) * sl);
      qfb[j] = (_Float16)((((float)qrb[j] - mean) * rstd * gwp[16 + j] + gbp[16 + j]) * sl);
    }
  }

  const _Float16* gK = Ks + (long)bh * 65536 + ((wv >> 2) * 2048 + (wv & 3) * 512) + lane * 8;
  const _Float16* gV = Vs + (long)bh * 65536 + ((wv >> 2) * 2048 + (wv & 3) * 512) + lane * 8;

  __shared__ __align__(16) char smem[32768];   // [2 bufs][K 8KB | V 8KB]; reused for reduction
  const int ldsK = wv * 1024 + lane * 16;
  const int ldsV = 8192 + wv * 1024 + lane * 16;

  floatx16 z16;
  #pragma unroll
  for (int i = 0; i < 16; i++) z16[i] = 0.f;
  floatx16 accA = z16, accB = z16;

  // prologue: stage pair 0 into buf0
  {
    uint4 a = *(const uint4*)gK;
    uint4 c = *(const uint4*)gV;
    *(uint4*)(smem + ldsK) = a;
    *(uint4*)(smem + ldsV) = c;
  }
  __syncthreads();

  #pragma unroll 2
  for (int i = 0; i < 16; i++) {
    const int cur = (i & 1) << 14;
    uint4 sa, sc;
    if (i < 15) {                                  // issue next-pair loads early
      sa = *(const uint4*)(gK + (i + 1) * 4096);
      sc = *(const uint4*)(gV + (i + 1) * 4096);
    }
    #pragma unroll
    for (int j = 0; j < 2; j++) {
      const char* Kb = smem + cur + j * 4096;
      const char* Vb = smem + cur + 8192 + j * 4096;
      half8 kfa = *(const half8*)(Kb + (2 * br) * 1024 + lane * 16);
      half8 kfb = *(const half8*)(Kb + (2 * br + 1) * 1024 + lane * 16);

      floatx16 s = __builtin_amdgcn_mfma_f32_32x32x16_f16(kfa, qfa, z16, 0, 0, 0);
      s = __builtin_amdgcn_mfma_f32_32x32x16_f16(kfb, qfb, s, 0, 0, 0);

      half8 vf0 = *(const half8*)(Vb + lane * 16);
      half8 vf1 = *(const half8*)(Vb + 1024 + lane * 16);
      half8 vf2 = *(const half8*)(Vb + 2048 + lane * 16);
      half8 vf3 = *(const half8*)(Vb + 3072 + lane * 16);

      uint32_t u[8];
      #pragma unroll
      for (int q = 0; q < 8; q++)
        u[q] = pkrtz(fexp2(s[2 * q]), fexp2(s[2 * q + 1]));

      union { uint32_t u[4]; half8 h; } pa;
      pa.u[0] = u[0]; pa.u[1] = u[1]; pa.u[2] = u[2]; pa.u[3] = u[3];
      half8 pc0 = pa.h;
      pa.u[0] = u[4]; pa.u[1] = u[5]; pa.u[2] = u[6]; pa.u[3] = u[7];
      half8 pc1 = pa.h;

      accA = __builtin_amdgcn_mfma_f32_32x32x16_f16(pc0, vf0, accA, 0, 0, 0);
      accA = __builtin_amdgcn_mfma_f32_32x32x16_f16(pc1, vf1, accA, 0, 0, 0);
      accB = __builtin_amdgcn_mfma_f32_32x32x16_f16(pc0, vf2, accB, 0, 0, 0);
      accB = __builtin_amdgcn_mfma_f32_32x32x16_f16(pc1, vf3, accB, 0, 0, 0);
    }
    if (i < 15) {                                  // write into the other buffer
      *(uint4*)(smem + (cur ^ 16384) + ldsK) = sa;
      *(uint4*)(smem + (cur ^ 16384) + ldsV) = sc;
    }
    __syncthreads();
  }

  // branch combine: odd waves dump accs, even waves combine + write Y (flat f32)
  const int pairid = wv >> 1;
  float* rbuf = (float*)(smem + pairid * 8192);
  if (br == 1) {
    #pragma unroll
    for (int r = 0; r < 16; r++) {
      rbuf[r * 64 + lane] = accA[r];
      rbuf[(16 + r) * 64 + lane] = accB[r];
    }
  }
  __syncthreads();
  if (br == 0) {
    float a2a[16], a2b[16];
    #pragma unroll
    for (int r = 0; r < 16; r++) {
      a2a[r] = rbuf[r * 64 + lane];
      a2b[r] = rbuf[(16 + r) * 64 + lane];
    }
    float* Ybh = Y + (long)bh * 49152;
    const int src = (lane & 32) + 16;
    #pragma unroll
    for (int r = 0; r < 16; r++) {
      float i1 = __builtin_amdgcn_rcpf(__shfl(accB[r], src));
      float i2 = __builtin_amdgcn_rcpf(__shfl(a2b[r], src));
      int n = n0 + (r & 3) + 8 * ((r >> 2) & 3) + 4 * hi;
      float o0 = accA[r] * i1 - a2a[r] * i2;   // d = l31
      float o1 = accB[r] * i1 - a2b[r] * i2;   // d = 32 + l31 (valid < 48)
      int p0 = l31 >= 24;
      Ybh[p0 * 24576 + n * 24 + (l31 - p0 * 24)] = o0;
      if (l31 < 16) Ybh[24576 + n * 24 + 8 + l31] = o1;
    }
  }
}

// ---------------- proj GEMM: PWf @ Yt + b ----------------
__launch_bounds__(256, 4)
__global__ void k_proj(const _Float16* __restrict__ Yt, const _Float16* __restrict__ PWf,
                       const float* __restrict__ PB, float* __restrict__ out) {
  const int tid = threadIdx.x, lane = tid & 63, wv = tid >> 6, l15 = lane & 15, g = lane >> 4;
  const int o0 = blockIdx.x * 64, m0 = blockIdx.y * 64, b = blockIdx.z;

  const int mcol = m0 + wv * 16 + l15;
  const _Float16* yp = Yt + (long)b * 393216 + (long)mcol * 32 + g * 8;
  const _Float16* wfb = PWf + (long)(blockIdx.x * 48) * 512 + lane * 8;

  half8 yb[12];
  #pragma unroll
  for (int cb = 0; cb < 12; cb++) yb[cb] = *(const half8*)(yp + cb * 32768);

  floatx4 zero4 = {0.f, 0.f, 0.f, 0.f};
  floatx4 acc0 = zero4, acc1 = zero4, acc2 = zero4, acc3 = zero4;

  half8 A0 = *(const half8*)(wfb);
  half8 A1 = *(const half8*)(wfb + 12 * 512);
  half8 A2 = *(const half8*)(wfb + 24 * 512);
  half8 A3 = *(const half8*)(wfb + 36 * 512);
  #pragma unroll
  for (int cb = 0; cb < 12; cb++) {
    half8 c0 = A0, c1 = A1, c2 = A2, c3 = A3;
    if (cb < 11) {
      A0 = *(const half8*)(wfb + (cb + 1) * 512);
      A1 = *(const half8*)(wfb + (12 + cb + 1) * 512);
      A2 = *(const half8*)(wfb + (24 + cb + 1) * 512);
      A3 = *(const half8*)(wfb + (36 + cb + 1) * 512);
    }
    acc0 = __builtin_amdgcn_mfma_f32_16x16x32_f16(c0, yb[cb], acc0, 0, 0, 0);
    acc1 = __builtin_amdgcn_mfma_f32_16x16x32_f16(c1, yb[cb], acc1, 0, 0, 0);
    acc2 = __builtin_amdgcn_mfma_f32_16x16x32_f16(c2, yb[cb], acc2, 0, 0, 0);
    acc3 = __builtin_amdgcn_mfma_f32_16x16x32_f16(c3, yb[cb], acc3, 0, 0, 0);
  }

  floatx4 acc[4] = {acc0, acc1, acc2, acc3};
  #pragma unroll
  for (int rt = 0; rt < 4; rt++) {
    int o_ = o0 + rt * 16 + g * 4;
    #pragma unroll
    for (int r = 0; r < 4; r++) {
      out[(long)(b * 384 + o_ + r) * 1024 + mcol] = acc[rt][r] + PB[o_ + r];
    }
  }
}

extern "C" void kernel_launch(void* const* d_in, const int* in_sizes, int n_in,
                              void* d_out, int out_size, void* d_ws, size_t ws_size,
                              hipStream_t stream) {
  const float* x     = (const float*)d_in[0];
  const float* qkv_w = (const float*)d_in[1];
  const float* lam   = (const float*)d_in[2];
  const float* gw    = (const float*)d_in[3];
  const float* gb    = (const float*)d_in[4];
  const float* pw    = (const float*)d_in[5];
  const float* pb    = (const float*)d_in[6];
  float* out = (float*)d_out;
  char* ws = (char*)d_ws;
  _Float16* Qs  = (_Float16*)ws;
  _Float16* Ks  = (_Float16*)(ws + 8388608);
  _Float16* Vs  = (_Float16*)(ws + 16777216);
  float* Y        = (float*)(ws + 25165824);
  float* partial  = (float*)(ws + 37748736);
  _Float16* Xt  = (_Float16*)(ws + 37752832);
  _Float16* Yt  = (_Float16*)(ws + 44044288);
  _Float16* Wf  = (_Float16*)(ws + 50335744);
  _Float16* PWf = (_Float16*)(ws + 51220480);

  hipLaunchKernelGGL(k_pack,    dim3(216),        dim3(256), 0, stream, qkv_w, Wf, 55296);
  hipLaunchKernelGGL(k_pack,    dim3(72),         dim3(256), 0, stream, pw, PWf, 18432);
  hipLaunchKernelGGL(k_tr,      dim3(12, 4, 8),   dim3(256), 0, stream, x, Xt);
  hipLaunchKernelGGL(k_qkv,     dim3(24, 16, 8),  dim3(256), 0, stream, Xt, Wf, Qs, Ks, Vs);
  hipLaunchKernelGGL(k_gnstats, dim3(128),        dim3(256), 0, stream, Qs, partial);
  hipLaunchKernelGGL(k_attn,    dim3(512),        dim3(512), 0, stream, Qs, Ks, Vs, partial, lam, gw, gb, Y);
  hipLaunchKernelGGL(k_tr,      dim3(12, 4, 8),   dim3(256), 0, stream, Y, Yt);
  hipLaunchKernelGGL(k_proj,    dim3(6, 16, 8),   dim3(256), 0, stream, Yt, PWf, pb, out);
}